// Round 2
// baseline (356.827 us; speedup 1.0000x reference)
//
#include <hip/hip_runtime.h>
#include <math.h>

#define NN 100000
#define NE 640000
#define ET (NE + NN)          // edges + self loops = 740000
#define FIN 128
#define C1 64
#define C2 16
#define NEG_SLOPE 0.2f
#define SCAN_B 1024
#define SCAN_NB ((NN + SCAN_B - 1) / SCAN_B)   // 98

static __device__ __forceinline__ float lrelu(float x) { return x > 0.f ? x : NEG_SLOPE * x; }
static __device__ __forceinline__ float softplusf(float x) {
    return fmaxf(x, 0.f) + log1pf(expf(-fabsf(x)));
}

// ---------------- CSR build ----------------
__global__ void k_zero(int* __restrict__ deg, int* __restrict__ cnt) {
    int i = blockIdx.x * blockDim.x + threadIdx.x;
    if (i < NN) { deg[i] = 0; cnt[i] = 0; }
}

__global__ void k_hist(const int* __restrict__ ei, int* __restrict__ deg) {
    int i = blockIdx.x * blockDim.x + threadIdx.x;
    if (i >= ET) return;
    int dst = (i < NE) ? ei[NE + i] : (i - NE);
    atomicAdd(&deg[dst], 1);
}

__global__ void k_scan1(const int* __restrict__ deg, int* __restrict__ incl, int* __restrict__ bsum) {
    __shared__ int s[SCAN_B];
    int ti = threadIdx.x;
    int i = blockIdx.x * SCAN_B + ti;
    int v = (i < NN) ? deg[i] : 0;
    s[ti] = v; __syncthreads();
    for (int d = 1; d < SCAN_B; d <<= 1) {
        int t = (ti >= d) ? s[ti - d] : 0;
        __syncthreads();
        s[ti] += t;
        __syncthreads();
    }
    if (i < NN) incl[i] = s[ti];
    if (ti == SCAN_B - 1) bsum[blockIdx.x] = s[ti];
}

__global__ void k_scan2(const int* __restrict__ bsum, int* __restrict__ boff) {
    if (threadIdx.x == 0 && blockIdx.x == 0) {
        int r = 0;
        for (int j = 0; j < SCAN_NB; j++) { boff[j] = r; r += bsum[j]; }
    }
}

__global__ void k_scan3(const int* __restrict__ incl, const int* __restrict__ boff, int* __restrict__ rowptr) {
    int i = blockIdx.x * blockDim.x + threadIdx.x;
    if (i < NN) rowptr[i + 1] = incl[i] + boff[i >> 10];
    if (i == 0) rowptr[0] = 0;
}

__global__ void k_scatter(const int* __restrict__ ei, const int* __restrict__ rowptr,
                          int* __restrict__ cnt, int* __restrict__ csr_src) {
    int i = blockIdx.x * blockDim.x + threadIdx.x;
    if (i >= ET) return;
    int src, dst;
    if (i < NE) { src = ei[i]; dst = ei[NE + i]; }
    else        { src = i - NE; dst = src; }
    int pos = rowptr[dst] + atomicAdd(&cnt[dst], 1);
    csr_src[pos] = src;
}

// ---------------- Layer 1 GEMM: h1 = x @ W1, + attention dots ----------------
#define K3_RPW 16
__global__ __launch_bounds__(256, 2) void k_gemm1(
        const float* __restrict__ x, const float* __restrict__ W1,
        const float* __restrict__ attS, const float* __restrict__ attD,
        float* __restrict__ h1, float* __restrict__ as1, float* __restrict__ ad1) {
    __shared__ float xbuf[4][2][FIN];
    int lane = threadIdx.x & 63;
    int wv = threadIdx.x >> 6;
    int base = (blockIdx.x * 4 + wv) * K3_RPW;
    if (base >= NN) return;
    float w[FIN];
#pragma unroll
    for (int k = 0; k < FIN; k++) w[k] = W1[k * C1 + lane];
    float ats = attS[lane], atd = attD[lane];
    int nrows = NN - base; if (nrows > K3_RPW) nrows = K3_RPW;
    float2 xv = *reinterpret_cast<const float2*>(&x[(size_t)base * FIN + lane * 2]);
    for (int r = 0; r < nrows; r++) {
        *reinterpret_cast<float2*>(&xbuf[wv][r & 1][lane * 2]) = xv;
        __builtin_amdgcn_wave_barrier();
        if (r + 1 < nrows)
            xv = *reinterpret_cast<const float2*>(&x[(size_t)(base + r + 1) * FIN + lane * 2]);
        float c0 = 0.f, c1 = 0.f, c2 = 0.f, c3 = 0.f;
#pragma unroll
        for (int k4 = 0; k4 < FIN / 4; k4++) {
            float4 xk = *reinterpret_cast<const float4*>(&xbuf[wv][r & 1][k4 * 4]);
            c0 = fmaf(xk.x, w[k4 * 4 + 0], c0);
            c1 = fmaf(xk.y, w[k4 * 4 + 1], c1);
            c2 = fmaf(xk.z, w[k4 * 4 + 2], c2);
            c3 = fmaf(xk.w, w[k4 * 4 + 3], c3);
        }
        __builtin_amdgcn_wave_barrier();
        float acc = (c0 + c1) + (c2 + c3);
        int n = base + r;
        h1[(size_t)n * C1 + lane] = acc;
        float s1 = acc * ats, d1 = acc * atd;
#pragma unroll
        for (int off = 32; off; off >>= 1) {
            s1 += __shfl_xor(s1, off);
            d1 += __shfl_xor(d1, off);
        }
        if (lane == 0) { as1[n] = s1; ad1[n] = d1; }
    }
}

// ---------------- Layer 1 aggregate + bias + ixz1 + elu ----------------
__global__ __launch_bounds__(256, 8) void k_agg1(
        const int* __restrict__ rowptr, const int* __restrict__ csr_src,
        const float* __restrict__ h1, const float* __restrict__ as1, const float* __restrict__ ad1,
        const float* __restrict__ b1,
        float* __restrict__ helu, float* __restrict__ ixz1) {
    int lane = threadIdx.x & 63;
    int node = (blockIdx.x * blockDim.x + threadIdx.x) >> 6;
    if (node >= NN) return;
    int start = rowptr[node], end = rowptr[node + 1];
    int deg = end - start;
    float adn = ad1[node];

    if (deg <= 64) {
        // lane-parallel edge prep: one coalesced csr load + parallel as1 gather
        int s_l = csr_src[start + (lane < deg ? lane : 0)];
        float al = (lane < deg) ? lrelu(as1[s_l] + adn) : -1e30f;
        float m = al;
#pragma unroll
        for (int off = 32; off; off >>= 1) m = fmaxf(m, __shfl_xor(m, off));
        float wl = (lane < deg) ? expf(al - m) : 0.f;
        float den = wl;
#pragma unroll
        for (int off = 32; off; off >>= 1) den += __shfl_xor(den, off);

        // 16 lanes x float4 = 64 features, 4 edges in flight
        int f4 = lane & 15, g = lane >> 4;
        float4 acc = make_float4(0.f, 0.f, 0.f, 0.f);
        for (int e0 = 0; e0 < deg; e0 += 4) {
            int e = e0 + g;
            int ee = (e < deg) ? e : 0;
            float wgt = __shfl(wl, ee);
            int s = __shfl(s_l, ee);
            if (e < deg) {
                float4 hv = *reinterpret_cast<const float4*>(&h1[(size_t)s * C1 + f4 * 4]);
                acc.x = fmaf(wgt, hv.x, acc.x);
                acc.y = fmaf(wgt, hv.y, acc.y);
                acc.z = fmaf(wgt, hv.z, acc.z);
                acc.w = fmaf(wgt, hv.w, acc.w);
            }
        }
#pragma unroll
        for (int off = 16; off <= 32; off <<= 1) {
            acc.x += __shfl_xor(acc.x, off);
            acc.y += __shfl_xor(acc.y, off);
            acc.z += __shfl_xor(acc.z, off);
            acc.w += __shfl_xor(acc.w, off);
        }
        float inv = 1.f / (den + 1e-16f);
        float4 bv = *reinterpret_cast<const float4*>(&b1[f4 * 4]);
        float4 o;
        o.x = acc.x * inv + bv.x;
        o.y = acc.y * inv + bv.y;
        o.z = acc.z * inv + bv.z;
        o.w = acc.w * inv + bv.w;
        float4 he;
        he.x = o.x > 0.f ? o.x : expm1f(o.x);
        he.y = o.y > 0.f ? o.y : expm1f(o.y);
        he.z = o.z > 0.f ? o.z : expm1f(o.z);
        he.w = o.w > 0.f ? o.w : expm1f(o.w);
        if (lane < 16)
            *reinterpret_cast<float4*>(&helu[(size_t)node * C1 + f4 * 4]) = he;
        float4 oth;
        oth.x = __shfl_down(o.x, 8);
        oth.y = __shfl_down(o.y, 8);
        oth.z = __shfl_down(o.z, 8);
        oth.w = __shfl_down(o.w, 8);
        if (lane < 8) {
            float4 kl;
            float sd;
            sd = softplusf(oth.x) + 1e-10f; kl.x = -logf(sd) + 0.5f * (sd * sd + o.x * o.x - 1.f);
            sd = softplusf(oth.y) + 1e-10f; kl.y = -logf(sd) + 0.5f * (sd * sd + o.y * o.y - 1.f);
            sd = softplusf(oth.z) + 1e-10f; kl.z = -logf(sd) + 0.5f * (sd * sd + o.z * o.z - 1.f);
            sd = softplusf(oth.w) + 1e-10f; kl.w = -logf(sd) + 0.5f * (sd * sd + o.w * o.w - 1.f);
            *reinterpret_cast<float4*>(&ixz1[(size_t)node * 32 + lane * 4]) = kl;
        }
    } else {
        // fallback: serial (deg > 64 is vanishingly rare)
        float m = -1e30f;
        for (int e = start + lane; e < end; e += 64) {
            int s = csr_src[e];
            m = fmaxf(m, lrelu(as1[s] + adn));
        }
#pragma unroll
        for (int off = 32; off; off >>= 1) m = fmaxf(m, __shfl_xor(m, off));
        float acc = 0.f, den = 0.f;
        for (int e = start; e < end; e++) {
            int s = csr_src[e];
            float a = lrelu(as1[s] + adn);
            float wgt = expf(a - m);
            den += wgt;
            acc += wgt * h1[(size_t)s * C1 + lane];
        }
        float out = acc / (den + 1e-16f) + b1[lane];
        helu[(size_t)node * C1 + lane] = out > 0.f ? out : expm1f(out);
        float other = __shfl_down(out, 32);
        if (lane < 32) {
            float sd = softplusf(other) + 1e-10f;
            float kl = -logf(sd) + 0.5f * (sd * sd + out * out - 1.f);
            ixz1[(size_t)node * 32 + lane] = kl;
        }
    }
}

// ---------------- Layer 2 GEMM: h2 = helu @ W2, + attention dots ----------------
__global__ __launch_bounds__(256, 4) void k_gemm2(
        const float* __restrict__ helu, const float* __restrict__ W2,
        const float* __restrict__ attS, const float* __restrict__ attD,
        float* __restrict__ h2, float* __restrict__ as2, float* __restrict__ ad2) {
    int lane = threadIdx.x & 63;
    int wv = threadIdx.x >> 6;
    int f = lane & 15, rg = lane >> 4;
    int n0 = (blockIdx.x * 4 + wv) * 4;
    if (n0 >= NN) return;
    float w[C1];
#pragma unroll
    for (int k = 0; k < C1; k++) w[k] = W2[k * C2 + f];
    int n = n0 + rg;
    bool valid = n < NN;
    float acc = 0.f;
    if (valid) {
        const float* xr = &helu[(size_t)n * C1];
#pragma unroll
        for (int k4 = 0; k4 < C1 / 4; k4++) {
            float4 xk = *reinterpret_cast<const float4*>(&xr[k4 * 4]);
            acc = fmaf(xk.x, w[k4 * 4 + 0], acc);
            acc = fmaf(xk.y, w[k4 * 4 + 1], acc);
            acc = fmaf(xk.z, w[k4 * 4 + 2], acc);
            acc = fmaf(xk.w, w[k4 * 4 + 3], acc);
        }
        h2[(size_t)n * C2 + f] = acc;
    }
    float s1 = acc * attS[f], d1 = acc * attD[f];
#pragma unroll
    for (int off = 1; off < 16; off <<= 1) {
        s1 += __shfl_xor(s1, off);
        d1 += __shfl_xor(d1, off);
    }
    if (valid && f == 0) { as2[n] = s1; ad2[n] = d1; }
}

// ---------------- Layer 2 aggregate + bias + out2 + ixz2 ----------------
__global__ __launch_bounds__(256, 8) void k_agg2(
        const int* __restrict__ rowptr, const int* __restrict__ csr_src,
        const float* __restrict__ h2, const float* __restrict__ as2, const float* __restrict__ ad2,
        const float* __restrict__ b2,
        float* __restrict__ out2, float* __restrict__ ixz2) {
    int lane = threadIdx.x & 63;
    int node = (blockIdx.x * blockDim.x + threadIdx.x) >> 6;
    if (node >= NN) return;
    int start = rowptr[node], end = rowptr[node + 1];
    int deg = end - start;
    float adn = ad2[node];

    if (deg <= 64) {
        int s_l = csr_src[start + (lane < deg ? lane : 0)];
        float al = (lane < deg) ? lrelu(as2[s_l] + adn) : -1e30f;
        float m = al;
#pragma unroll
        for (int off = 32; off; off >>= 1) m = fmaxf(m, __shfl_xor(m, off));
        float wl = (lane < deg) ? expf(al - m) : 0.f;
        float den = wl;
#pragma unroll
        for (int off = 32; off; off >>= 1) den += __shfl_xor(den, off);

        // 4 lanes x float4 = 16 features, 16 edges in flight
        int f4 = lane & 3, g = lane >> 2;
        float4 acc = make_float4(0.f, 0.f, 0.f, 0.f);
        for (int e0 = 0; e0 < deg; e0 += 16) {
            int e = e0 + g;
            int ee = (e < deg) ? e : 0;
            float wgt = __shfl(wl, ee);
            int s = __shfl(s_l, ee);
            if (e < deg) {
                float4 hv = *reinterpret_cast<const float4*>(&h2[(size_t)s * C2 + f4 * 4]);
                acc.x = fmaf(wgt, hv.x, acc.x);
                acc.y = fmaf(wgt, hv.y, acc.y);
                acc.z = fmaf(wgt, hv.z, acc.z);
                acc.w = fmaf(wgt, hv.w, acc.w);
            }
        }
#pragma unroll
        for (int off = 4; off <= 32; off <<= 1) {
            acc.x += __shfl_xor(acc.x, off);
            acc.y += __shfl_xor(acc.y, off);
            acc.z += __shfl_xor(acc.z, off);
            acc.w += __shfl_xor(acc.w, off);
        }
        float inv = 1.f / (den + 1e-16f);
        float4 bv = *reinterpret_cast<const float4*>(&b2[f4 * 4]);
        float4 o;
        o.x = acc.x * inv + bv.x;
        o.y = acc.y * inv + bv.y;
        o.z = acc.z * inv + bv.z;
        o.w = acc.w * inv + bv.w;
        if (lane < 4)
            *reinterpret_cast<float4*>(&out2[(size_t)node * C2 + f4 * 4]) = o;
        float4 oth;
        oth.x = __shfl_down(o.x, 2);
        oth.y = __shfl_down(o.y, 2);
        oth.z = __shfl_down(o.z, 2);
        oth.w = __shfl_down(o.w, 2);
        if (lane < 2) {
            float4 kl;
            float sd;
            sd = softplusf(oth.x) + 1e-10f; kl.x = -logf(sd) + 0.5f * (sd * sd + o.x * o.x - 1.f);
            sd = softplusf(oth.y) + 1e-10f; kl.y = -logf(sd) + 0.5f * (sd * sd + o.y * o.y - 1.f);
            sd = softplusf(oth.z) + 1e-10f; kl.z = -logf(sd) + 0.5f * (sd * sd + o.z * o.z - 1.f);
            sd = softplusf(oth.w) + 1e-10f; kl.w = -logf(sd) + 0.5f * (sd * sd + o.w * o.w - 1.f);
            *reinterpret_cast<float4*>(&ixz2[(size_t)node * 8 + lane * 4]) = kl;
        }
    } else {
        int f = lane & 15, g = lane >> 4;
        float m = -1e30f;
        for (int e = start + lane; e < end; e += 64) {
            int s = csr_src[e];
            m = fmaxf(m, lrelu(as2[s] + adn));
        }
#pragma unroll
        for (int off = 32; off; off >>= 1) m = fmaxf(m, __shfl_xor(m, off));
        float acc = 0.f, den = 0.f;
        for (int e0 = start; e0 < end; e0 += 4) {
            int e = e0 + g;
            if (e < end) {
                int s = csr_src[e];
                float a = lrelu(as2[s] + adn);
                float wgt = expf(a - m);
                den += wgt;
                acc += wgt * h2[(size_t)s * C2 + f];
            }
        }
        acc += __shfl_xor(acc, 16); acc += __shfl_xor(acc, 32);
        den += __shfl_xor(den, 16); den += __shfl_xor(den, 32);
        float out = acc / (den + 1e-16f) + b2[f];
        if (lane < 16) out2[(size_t)node * C2 + f] = out;
        float other = __shfl_down(out, 8);
        if (lane < 8) {
            float sd = softplusf(other) + 1e-10f;
            float kl = -logf(sd) + 0.5f * (sd * sd + out * out - 1.f);
            ixz2[(size_t)node * 8 + lane] = kl;
        }
    }
}

extern "C" void kernel_launch(void* const* d_in, const int* in_sizes, int n_in,
                              void* d_out, int out_size, void* d_ws, size_t ws_size,
                              hipStream_t stream) {
    const float* x     = (const float*)d_in[0];
    const int*   ei    = (const int*)d_in[1];
    const float* W1    = (const float*)d_in[2];
    const float* aS1   = (const float*)d_in[3];
    const float* aD1   = (const float*)d_in[4];
    const float* b1    = (const float*)d_in[5];
    const float* W2    = (const float*)d_in[6];
    const float* aS2   = (const float*)d_in[7];
    const float* aD2   = (const float*)d_in[8];
    const float* b2    = (const float*)d_in[9];

    float* out = (float*)d_out;
    float* out2 = out;                         // N*16
    float* ixz1 = out + (size_t)NN * C2;       // N*32
    float* ixz2 = ixz1 + (size_t)NN * 32;      // N*8

    char* p = (char*)d_ws;
    auto alloc = [&](size_t bytes) -> void* {
        void* r = (void*)p;
        p += (bytes + 255) & ~(size_t)255;
        return r;
    };
    int* deg     = (int*)alloc((size_t)NN * 4);
    int* cnt     = (int*)alloc((size_t)NN * 4);
    int* incl    = (int*)alloc((size_t)NN * 4);
    int* bsum    = (int*)alloc(512 * 4);
    int* boff    = (int*)alloc(512 * 4);
    int* rowptr  = (int*)alloc((size_t)(NN + 1) * 4);
    int* csr_src = (int*)alloc((size_t)ET * 4);
    float* h1    = (float*)alloc((size_t)NN * C1 * 4);
    float* as1   = (float*)alloc((size_t)NN * 4);
    float* ad1   = (float*)alloc((size_t)NN * 4);
    float* helu  = (float*)alloc((size_t)NN * C1 * 4);
    float* h2    = (float*)alloc((size_t)NN * C2 * 4);
    float* as2   = (float*)alloc((size_t)NN * 4);
    float* ad2   = (float*)alloc((size_t)NN * 4);
    (void)ws_size; (void)in_sizes; (void)n_in; (void)out_size;

    // CSR build
    k_zero<<<(NN + 255) / 256, 256, 0, stream>>>(deg, cnt);
    k_hist<<<(ET + 255) / 256, 256, 0, stream>>>(ei, deg);
    k_scan1<<<SCAN_NB, SCAN_B, 0, stream>>>(deg, incl, bsum);
    k_scan2<<<1, 64, 0, stream>>>(bsum, boff);
    k_scan3<<<(NN + 255) / 256, 256, 0, stream>>>(incl, boff, rowptr);
    k_scatter<<<(ET + 255) / 256, 256, 0, stream>>>(ei, rowptr, cnt, csr_src);

    // Layer 1
    k_gemm1<<<(NN + 4 * K3_RPW - 1) / (4 * K3_RPW), 256, 0, stream>>>(x, W1, aS1, aD1, h1, as1, ad1);
    k_agg1<<<(NN + 3) / 4, 256, 0, stream>>>(rowptr, csr_src, h1, as1, ad1, b1, helu, ixz1);

    // Layer 2
    k_gemm2<<<(NN + 15) / 16, 256, 0, stream>>>(helu, W2, aS2, aD2, h2, as2, ad2);
    k_agg2<<<(NN + 3) / 4, 256, 0, stream>>>(rowptr, csr_src, h2, as2, ad2, b2, out2, ixz2);
}

// Round 3
// 264.517 us; speedup vs baseline: 1.3490x; 1.3490x over previous
//
#include <hip/hip_runtime.h>
#include <math.h>

#define NN 100000
#define NE 640000
#define ET (NE + NN)          // edges + self loops = 740000
#define FIN 128
#define C1 64
#define C2 16
#define NEG_SLOPE 0.2f
#define SCAN_B 1024
#define SCAN_NB ((NN + SCAN_B - 1) / SCAN_B)   // 98

typedef unsigned int uint32;
typedef unsigned short ushort16;

static __device__ __forceinline__ float lrelu(float x) { return x > 0.f ? x : NEG_SLOPE * x; }
static __device__ __forceinline__ float softplusf(float x) {
    return fmaxf(x, 0.f) + log1pf(expf(-fabsf(x)));
}
static __device__ __forceinline__ unsigned short f2bf(float f) {   // RNE
    uint32 u = __float_as_uint(f);
    u += 0x7fffu + ((u >> 16) & 1u);
    return (unsigned short)(u >> 16);
}
static __device__ __forceinline__ float bf2f_lo(uint32 p) { return __uint_as_float(p << 16); }
static __device__ __forceinline__ float bf2f_hi(uint32 p) { return __uint_as_float(p & 0xffff0000u); }

// ---------------- CSR build ----------------
__global__ void k_zero(int* __restrict__ deg, int* __restrict__ cnt) {
    int i = blockIdx.x * blockDim.x + threadIdx.x;
    if (i < NN) { deg[i] = 0; cnt[i] = 0; }
}

__global__ void k_hist(const int* __restrict__ ei, int* __restrict__ deg) {
    int i = blockIdx.x * blockDim.x + threadIdx.x;
    if (i >= ET) return;
    int dst = (i < NE) ? ei[NE + i] : (i - NE);
    atomicAdd(&deg[dst], 1);
}

__global__ void k_scan1(const int* __restrict__ deg, int* __restrict__ incl, int* __restrict__ bsum) {
    __shared__ int s[SCAN_B];
    int ti = threadIdx.x;
    int i = blockIdx.x * SCAN_B + ti;
    int v = (i < NN) ? deg[i] : 0;
    s[ti] = v; __syncthreads();
    for (int d = 1; d < SCAN_B; d <<= 1) {
        int t = (ti >= d) ? s[ti - d] : 0;
        __syncthreads();
        s[ti] += t;
        __syncthreads();
    }
    if (i < NN) incl[i] = s[ti];
    if (ti == SCAN_B - 1) bsum[blockIdx.x] = s[ti];
}

__global__ void k_scan2(const int* __restrict__ bsum, int* __restrict__ boff) {
    if (threadIdx.x == 0 && blockIdx.x == 0) {
        int r = 0;
        for (int j = 0; j < SCAN_NB; j++) { boff[j] = r; r += bsum[j]; }
    }
}

__global__ void k_scan3(const int* __restrict__ incl, const int* __restrict__ boff, int* __restrict__ rowptr) {
    int i = blockIdx.x * blockDim.x + threadIdx.x;
    if (i < NN) rowptr[i + 1] = incl[i] + boff[i >> 10];
    if (i == 0) rowptr[0] = 0;
}

__global__ void k_scatter(const int* __restrict__ ei, const int* __restrict__ rowptr,
                          int* __restrict__ cnt, int* __restrict__ csr_src) {
    int i = blockIdx.x * blockDim.x + threadIdx.x;
    if (i >= ET) return;
    int src, dst;
    if (i < NE) { src = ei[i]; dst = ei[NE + i]; }
    else        { src = i - NE; dst = src; }
    int pos = rowptr[dst] + atomicAdd(&cnt[dst], 1);
    csr_src[pos] = src;
}

// ---------------- Layer 1 GEMM: h1 = x @ W1 (bf16 out), + attention dots ----------------
#define G1_RPW 16
__global__ __launch_bounds__(256, 2) void k_gemm1(
        const float* __restrict__ x, const float* __restrict__ W1,
        const float* __restrict__ attS, const float* __restrict__ attD,
        unsigned short* __restrict__ h1b, float* __restrict__ as1, float* __restrict__ ad1) {
    __shared__ float xbuf[4][2][2][FIN];   // wave, buf, row-of-pair, k
    int lane = threadIdx.x & 63;
    int wv = threadIdx.x >> 6;
    int base = (blockIdx.x * 4 + wv) * G1_RPW;
    if (base >= NN) return;
    float w[FIN];
#pragma unroll
    for (int k = 0; k < FIN; k++) w[k] = W1[k * C1 + lane];
    float ats = attS[lane], atd = attD[lane];
    int nrows = NN - base; if (nrows > G1_RPW) nrows = G1_RPW;

    float2 xa = *reinterpret_cast<const float2*>(&x[(size_t)base * FIN + lane * 2]);
    float2 xb = xa;
    if (1 < nrows) xb = *reinterpret_cast<const float2*>(&x[(size_t)(base + 1) * FIN + lane * 2]);
    int buf = 0;
    for (int r0 = 0; r0 < nrows; r0 += 2) {
        *reinterpret_cast<float2*>(&xbuf[wv][buf][0][lane * 2]) = xa;
        *reinterpret_cast<float2*>(&xbuf[wv][buf][1][lane * 2]) = xb;
        __builtin_amdgcn_wave_barrier();
        // prefetch next pair (issued before the FMA block so vmcnt hides under compute)
        int rn = r0 + 2;
        if (rn < nrows) {
            xa = *reinterpret_cast<const float2*>(&x[(size_t)(base + rn) * FIN + lane * 2]);
            if (rn + 1 < nrows)
                xb = *reinterpret_cast<const float2*>(&x[(size_t)(base + rn + 1) * FIN + lane * 2]);
        }
        float a0 = 0.f, a1 = 0.f, b0 = 0.f, b1 = 0.f;
#pragma unroll
        for (int k4 = 0; k4 < FIN / 4; k4++) {
            float4 va = *reinterpret_cast<const float4*>(&xbuf[wv][buf][0][k4 * 4]);
            float4 vb = *reinterpret_cast<const float4*>(&xbuf[wv][buf][1][k4 * 4]);
            a0 = fmaf(va.x, w[k4 * 4 + 0], a0);
            a1 = fmaf(va.y, w[k4 * 4 + 1], a1);
            a0 = fmaf(va.z, w[k4 * 4 + 2], a0);
            a1 = fmaf(va.w, w[k4 * 4 + 3], a1);
            b0 = fmaf(vb.x, w[k4 * 4 + 0], b0);
            b1 = fmaf(vb.y, w[k4 * 4 + 1], b1);
            b0 = fmaf(vb.z, w[k4 * 4 + 2], b0);
            b1 = fmaf(vb.w, w[k4 * 4 + 3], b1);
        }
        __builtin_amdgcn_wave_barrier();
        buf ^= 1;
        float accA = a0 + a1;
        float accB = b0 + b1;
        int nA = base + r0;
        h1b[(size_t)nA * C1 + lane] = f2bf(accA);
        bool hasB = (r0 + 1) < nrows;
        if (hasB) h1b[(size_t)(nA + 1) * C1 + lane] = f2bf(accB);
        float sA = accA * ats, dA = accA * atd;
        float sB = accB * ats, dB = accB * atd;
#pragma unroll
        for (int off = 32; off; off >>= 1) {
            sA += __shfl_xor(sA, off);
            dA += __shfl_xor(dA, off);
            sB += __shfl_xor(sB, off);
            dB += __shfl_xor(dB, off);
        }
        if (lane == 0) {
            as1[nA] = sA; ad1[nA] = dA;
            if (hasB) { as1[nA + 1] = sB; ad1[nA + 1] = dB; }
        }
    }
}

// ---------------- Layer 1 aggregate + bias + ixz1 + elu ----------------
__global__ __launch_bounds__(256, 8) void k_agg1(
        const int* __restrict__ rowptr, const int* __restrict__ csr_src,
        const unsigned short* __restrict__ h1b, const float* __restrict__ as1, const float* __restrict__ ad1,
        const float* __restrict__ b1,
        float* __restrict__ helu, float* __restrict__ ixz1) {
    int lane = threadIdx.x & 63;
    int node = (blockIdx.x * blockDim.x + threadIdx.x) >> 6;
    if (node >= NN) return;
    int start = rowptr[node], end = rowptr[node + 1];
    int deg = end - start;
    float adn = ad1[node];
    float out;

    if (deg <= 64) {
        // lane-parallel edge prep
        int s_l = csr_src[start + (lane < deg ? lane : 0)];
        float al = (lane < deg) ? lrelu(as1[s_l] + adn) : -1e30f;
        float m = al;
#pragma unroll
        for (int off = 32; off; off >>= 1) m = fmaxf(m, __shfl_xor(m, off));
        float wl = (lane < deg) ? expf(al - m) : 0.f;
        float den = wl;
#pragma unroll
        for (int off = 32; off; off >>= 1) den += __shfl_xor(den, off);

        // gather: 16 lanes x ushort4(8B) = one bf16 row; 4 edges in flight
        int f4 = lane & 15, g = lane >> 4;
        float4 acc = make_float4(0.f, 0.f, 0.f, 0.f);
        for (int e0 = 0; e0 < deg; e0 += 4) {
            int e = e0 + g;
            int ee = (e < deg) ? e : 0;
            float wgt = __shfl(wl, ee);
            int s = __shfl(s_l, ee);
            if (e < deg) {
                uint2 p = *reinterpret_cast<const uint2*>(&h1b[(size_t)s * C1 + f4 * 4]);
                acc.x = fmaf(wgt, bf2f_lo(p.x), acc.x);
                acc.y = fmaf(wgt, bf2f_hi(p.x), acc.y);
                acc.z = fmaf(wgt, bf2f_lo(p.y), acc.z);
                acc.w = fmaf(wgt, bf2f_hi(p.y), acc.w);
            }
        }
#pragma unroll
        for (int off = 16; off <= 32; off <<= 1) {
            acc.x += __shfl_xor(acc.x, off);
            acc.y += __shfl_xor(acc.y, off);
            acc.z += __shfl_xor(acc.z, off);
            acc.w += __shfl_xor(acc.w, off);
        }
        // transpose back: lane l owns feature l (src lane l>>2, component l&3)
        int srcl = lane >> 2;
        float t0 = __shfl(acc.x, srcl);
        float t1 = __shfl(acc.y, srcl);
        float t2 = __shfl(acc.z, srcl);
        float t3 = __shfl(acc.w, srcl);
        float t01 = (lane & 1) ? t1 : t0;
        float t23 = (lane & 1) ? t3 : t2;
        float av = (lane & 2) ? t23 : t01;
        out = av / (den + 1e-16f) + b1[lane];
    } else {
        // fallback: serial
        float m = -1e30f;
        for (int e = start + lane; e < end; e += 64) {
            int s = csr_src[e];
            m = fmaxf(m, lrelu(as1[s] + adn));
        }
#pragma unroll
        for (int off = 32; off; off >>= 1) m = fmaxf(m, __shfl_xor(m, off));
        float acc = 0.f, den = 0.f;
        for (int e = start; e < end; e++) {
            int s = csr_src[e];
            float a = lrelu(as1[s] + adn);
            float wgt = expf(a - m);
            den += wgt;
            acc += wgt * __uint_as_float(((uint32)h1b[(size_t)s * C1 + lane]) << 16);
        }
        out = acc / (den + 1e-16f) + b1[lane];
    }
    // lane-parallel epilogue (feature = lane)
    helu[(size_t)node * C1 + lane] = out > 0.f ? out : expm1f(out);
    float other = __shfl_down(out, 32);
    if (lane < 32) {
        float sd = softplusf(other) + 1e-10f;
        float kl = -logf(sd) + 0.5f * (sd * sd + out * out - 1.f);
        ixz1[(size_t)node * 32 + lane] = kl;
    }
}

// ---------------- Layer 2 GEMM: h2 = helu @ W2 (bf16 out), + attention dots ----------------
__global__ __launch_bounds__(256, 4) void k_gemm2(
        const float* __restrict__ helu, const float* __restrict__ W2,
        const float* __restrict__ attS, const float* __restrict__ attD,
        unsigned short* __restrict__ h2b, float* __restrict__ as2, float* __restrict__ ad2) {
    int lane = threadIdx.x & 63;
    int wv = threadIdx.x >> 6;
    int f = lane & 15, rg = lane >> 4;
    int n0 = (blockIdx.x * 4 + wv) * 4;
    if (n0 >= NN) return;
    float w[C1];
#pragma unroll
    for (int k = 0; k < C1; k++) w[k] = W2[k * C2 + f];
    int n = n0 + rg;
    bool valid = n < NN;
    float acc = 0.f;
    if (valid) {
        const float* xr = &helu[(size_t)n * C1];
#pragma unroll
        for (int k4 = 0; k4 < C1 / 4; k4++) {
            float4 xk = *reinterpret_cast<const float4*>(&xr[k4 * 4]);
            acc = fmaf(xk.x, w[k4 * 4 + 0], acc);
            acc = fmaf(xk.y, w[k4 * 4 + 1], acc);
            acc = fmaf(xk.z, w[k4 * 4 + 2], acc);
            acc = fmaf(xk.w, w[k4 * 4 + 3], acc);
        }
        h2b[(size_t)n * C2 + f] = f2bf(acc);
    }
    float s1 = acc * attS[f], d1 = acc * attD[f];
#pragma unroll
    for (int off = 1; off < 16; off <<= 1) {
        s1 += __shfl_xor(s1, off);
        d1 += __shfl_xor(d1, off);
    }
    if (valid && f == 0) { as2[n] = s1; ad2[n] = d1; }
}

// ---------------- Layer 2 aggregate + bias + out2 + ixz2 ----------------
__global__ __launch_bounds__(256, 8) void k_agg2(
        const int* __restrict__ rowptr, const int* __restrict__ csr_src,
        const unsigned short* __restrict__ h2b, const float* __restrict__ as2, const float* __restrict__ ad2,
        const float* __restrict__ b2,
        float* __restrict__ out2, float* __restrict__ ixz2) {
    int lane = threadIdx.x & 63;
    int node = (blockIdx.x * blockDim.x + threadIdx.x) >> 6;
    if (node >= NN) return;
    int start = rowptr[node], end = rowptr[node + 1];
    int deg = end - start;
    float adn = ad2[node];
    float out = 0.f;

    if (deg <= 64) {
        int s_l = csr_src[start + (lane < deg ? lane : 0)];
        float al = (lane < deg) ? lrelu(as2[s_l] + adn) : -1e30f;
        float m = al;
#pragma unroll
        for (int off = 32; off; off >>= 1) m = fmaxf(m, __shfl_xor(m, off));
        float wl = (lane < deg) ? expf(al - m) : 0.f;
        float den = wl;
#pragma unroll
        for (int off = 32; off; off >>= 1) den += __shfl_xor(den, off);

        // gather: 8 lanes x ushort2(4B) = one bf16 row; 8 edges in flight
        int f4 = lane & 7, g = lane >> 3;
        float2 acc = make_float2(0.f, 0.f);
        for (int e0 = 0; e0 < deg; e0 += 8) {
            int e = e0 + g;
            int ee = (e < deg) ? e : 0;
            float wgt = __shfl(wl, ee);
            int s = __shfl(s_l, ee);
            if (e < deg) {
                uint32 p = *reinterpret_cast<const uint32*>(&h2b[(size_t)s * C2 + f4 * 2]);
                acc.x = fmaf(wgt, bf2f_lo(p), acc.x);
                acc.y = fmaf(wgt, bf2f_hi(p), acc.y);
            }
        }
#pragma unroll
        for (int off = 8; off <= 32; off <<= 1) {
            acc.x += __shfl_xor(acc.x, off);
            acc.y += __shfl_xor(acc.y, off);
        }
        // transpose: lane l (<16) owns feature l (src lane l>>1, component l&1)
        int srcl = lane >> 1;
        float t0 = __shfl(acc.x, srcl);
        float t1 = __shfl(acc.y, srcl);
        float av = (lane & 1) ? t1 : t0;
        out = av / (den + 1e-16f) + b2[lane & 15];
    } else {
        int f = lane & 15, g = lane >> 4;
        float m = -1e30f;
        for (int e = start + lane; e < end; e += 64) {
            int s = csr_src[e];
            m = fmaxf(m, lrelu(as2[s] + adn));
        }
#pragma unroll
        for (int off = 32; off; off >>= 1) m = fmaxf(m, __shfl_xor(m, off));
        float acc = 0.f, den = 0.f;
        for (int e0 = start; e0 < end; e0 += 4) {
            int e = e0 + g;
            if (e < end) {
                int s = csr_src[e];
                float a = lrelu(as2[s] + adn);
                float wgt = expf(a - m);
                den += wgt;
                acc += wgt * __uint_as_float(((uint32)h2b[(size_t)s * C2 + f]) << 16);
            }
        }
        acc += __shfl_xor(acc, 16); acc += __shfl_xor(acc, 32);
        den += __shfl_xor(den, 16); den += __shfl_xor(den, 32);
        out = acc / (den + 1e-16f) + b2[f];
    }
    // lane-parallel epilogue (feature = lane for lanes 0..15)
    if (lane < 16) out2[(size_t)node * C2 + lane] = out;
    float other = __shfl_down(out, 8);
    if (lane < 8) {
        float sd = softplusf(other) + 1e-10f;
        float kl = -logf(sd) + 0.5f * (sd * sd + out * out - 1.f);
        ixz2[(size_t)node * 8 + lane] = kl;
    }
}

extern "C" void kernel_launch(void* const* d_in, const int* in_sizes, int n_in,
                              void* d_out, int out_size, void* d_ws, size_t ws_size,
                              hipStream_t stream) {
    const float* x     = (const float*)d_in[0];
    const int*   ei    = (const int*)d_in[1];
    const float* W1    = (const float*)d_in[2];
    const float* aS1   = (const float*)d_in[3];
    const float* aD1   = (const float*)d_in[4];
    const float* b1    = (const float*)d_in[5];
    const float* W2    = (const float*)d_in[6];
    const float* aS2   = (const float*)d_in[7];
    const float* aD2   = (const float*)d_in[8];
    const float* b2    = (const float*)d_in[9];

    float* out = (float*)d_out;
    float* out2 = out;                         // N*16
    float* ixz1 = out + (size_t)NN * C2;       // N*32
    float* ixz2 = ixz1 + (size_t)NN * 32;      // N*8

    char* p = (char*)d_ws;
    auto alloc = [&](size_t bytes) -> void* {
        void* r = (void*)p;
        p += (bytes + 255) & ~(size_t)255;
        return r;
    };
    int* deg     = (int*)alloc((size_t)NN * 4);
    int* cnt     = (int*)alloc((size_t)NN * 4);
    int* incl    = (int*)alloc((size_t)NN * 4);
    int* bsum    = (int*)alloc(512 * 4);
    int* boff    = (int*)alloc(512 * 4);
    int* rowptr  = (int*)alloc((size_t)(NN + 1) * 4);
    int* csr_src = (int*)alloc((size_t)ET * 4);
    unsigned short* h1b = (unsigned short*)alloc((size_t)NN * C1 * 2);
    float* as1   = (float*)alloc((size_t)NN * 4);
    float* ad1   = (float*)alloc((size_t)NN * 4);
    float* helu  = (float*)alloc((size_t)NN * C1 * 4);
    unsigned short* h2b = (unsigned short*)alloc((size_t)NN * C2 * 2);
    float* as2   = (float*)alloc((size_t)NN * 4);
    float* ad2   = (float*)alloc((size_t)NN * 4);
    (void)ws_size; (void)in_sizes; (void)n_in; (void)out_size;

    // CSR build
    k_zero<<<(NN + 255) / 256, 256, 0, stream>>>(deg, cnt);
    k_hist<<<(ET + 255) / 256, 256, 0, stream>>>(ei, deg);
    k_scan1<<<SCAN_NB, SCAN_B, 0, stream>>>(deg, incl, bsum);
    k_scan2<<<1, 64, 0, stream>>>(bsum, boff);
    k_scan3<<<(NN + 255) / 256, 256, 0, stream>>>(incl, boff, rowptr);
    k_scatter<<<(ET + 255) / 256, 256, 0, stream>>>(ei, rowptr, cnt, csr_src);

    // Layer 1
    k_gemm1<<<(NN + 4 * G1_RPW - 1) / (4 * G1_RPW), 256, 0, stream>>>(x, W1, aS1, aD1, h1b, as1, ad1);
    k_agg1<<<(NN + 3) / 4, 256, 0, stream>>>(rowptr, csr_src, h1b, as1, ad1, b1, helu, ixz1);

    // Layer 2
    k_gemm2<<<(NN + 15) / 16, 256, 0, stream>>>(helu, W2, aS2, aD2, h2b, as2, ad2);
    k_agg2<<<(NN + 3) / 4, 256, 0, stream>>>(rowptr, csr_src, h2b, as2, ad2, b2, out2, ixz2);
}

// Round 4
// 229.274 us; speedup vs baseline: 1.5563x; 1.1537x over previous
//
#include <hip/hip_runtime.h>
#include <math.h>

#define NN 100000
#define NE 640000
#define ET (NE + NN)          // edges + self loops = 740000
#define FIN 128
#define C1 64
#define C2 16
#define NEG_SLOPE 0.2f
#define SCAN_B 1024
#define SCAN_NB ((NN + SCAN_B - 1) / SCAN_B)   // 98

typedef unsigned int uint32;
typedef __attribute__((ext_vector_type(8))) short bf16x8;
typedef __attribute__((ext_vector_type(4))) float f32x4;

static __device__ __forceinline__ float lrelu(float x) { return x > 0.f ? x : NEG_SLOPE * x; }
static __device__ __forceinline__ float softplusf(float x) {
    return fmaxf(x, 0.f) + log1pf(expf(-fabsf(x)));
}
static __device__ __forceinline__ unsigned short f2bf(float f) {   // RNE
    uint32 u = __float_as_uint(f);
    u += 0x7fffu + ((u >> 16) & 1u);
    return (unsigned short)(u >> 16);
}
static __device__ __forceinline__ float bf2f_lo(uint32 p) { return __uint_as_float(p << 16); }
static __device__ __forceinline__ float bf2f_hi(uint32 p) { return __uint_as_float(p & 0xffff0000u); }

// ---------------- CSR build ----------------
__global__ void k_zero(int* __restrict__ deg, int* __restrict__ cnt) {
    int i = blockIdx.x * blockDim.x + threadIdx.x;
    if (i < NN) { deg[i] = 0; cnt[i] = 0; }
}

__global__ void k_hist(const int* __restrict__ ei, int* __restrict__ deg) {
    int i = blockIdx.x * blockDim.x + threadIdx.x;
    if (i >= ET) return;
    int dst = (i < NE) ? ei[NE + i] : (i - NE);
    atomicAdd(&deg[dst], 1);
}

__global__ void k_scan1(const int* __restrict__ deg, int* __restrict__ incl, int* __restrict__ bsum) {
    __shared__ int s[SCAN_B];
    int ti = threadIdx.x;
    int i = blockIdx.x * SCAN_B + ti;
    int v = (i < NN) ? deg[i] : 0;
    s[ti] = v; __syncthreads();
    for (int d = 1; d < SCAN_B; d <<= 1) {
        int t = (ti >= d) ? s[ti - d] : 0;
        __syncthreads();
        s[ti] += t;
        __syncthreads();
    }
    if (i < NN) incl[i] = s[ti];
    if (ti == SCAN_B - 1) bsum[blockIdx.x] = s[ti];
}

__global__ void k_scan2(const int* __restrict__ bsum, int* __restrict__ boff) {
    if (threadIdx.x == 0 && blockIdx.x == 0) {
        int r = 0;
        for (int j = 0; j < SCAN_NB; j++) { boff[j] = r; r += bsum[j]; }
    }
}

__global__ void k_scan3(const int* __restrict__ incl, const int* __restrict__ boff, int* __restrict__ rowptr) {
    int i = blockIdx.x * blockDim.x + threadIdx.x;
    if (i < NN) rowptr[i + 1] = incl[i] + boff[i >> 10];
    if (i == 0) rowptr[0] = 0;
}

__global__ void k_scatter(const int* __restrict__ ei, const int* __restrict__ rowptr,
                          int* __restrict__ cnt, int* __restrict__ csr_src) {
    int i = blockIdx.x * blockDim.x + threadIdx.x;
    if (i >= ET) return;
    int src, dst;
    if (i < NE) { src = ei[i]; dst = ei[NE + i]; }
    else        { src = i - NE; dst = src; }
    int pos = rowptr[dst] + atomicAdd(&cnt[dst], 1);
    csr_src[pos] = src;
}

// ---------------- Layer 1 GEMM (MFMA bf16): h1 = x @ W1, + attention dots ----------------
// M=NN, K=128, N=64. Per wave: G1T tiles of 16 rows. 16 mfma_16x16x32 per tile.
#define G1T 2
__global__ __launch_bounds__(256, 3) void k_gemm1(
        const float* __restrict__ x, const float* __restrict__ W1,
        const float* __restrict__ attS, const float* __restrict__ attD,
        unsigned short* __restrict__ h1b, float* __restrict__ as1, float* __restrict__ ad1) {
    __shared__ uint32 xs[4][16][64];   // per-wave 16 rows x 128 bf16 (packed u32), slot-swizzled
    int lane = threadIdx.x & 63;
    int wv = threadIdx.x >> 6;
    int col = lane & 15;               // MFMA row (A) / col (B,C)
    int g = lane >> 4;                 // k-group
    int wbase = (blockIdx.x * 4 + wv) * (G1T * 16);
    if (wbase >= NN) return;

    // B fragments in registers: B[k][col] = W1[k*64+col], lane: col=lane&15(+16j), k=32t+8g+i
    bf16x8 bfr[4][4];
#pragma unroll
    for (int t = 0; t < 4; t++)
#pragma unroll
        for (int j = 0; j < 4; j++) {
            int c = col + j * 16;
#pragma unroll
            for (int i = 0; i < 8; i++)
                bfr[t][j][i] = (short)f2bf(W1[(t * 32 + g * 8 + i) * C1 + c]);
        }
    float ats[4], atd[4];
#pragma unroll
    for (int j = 0; j < 4; j++) { ats[j] = attS[col + j * 16]; atd[j] = attD[col + j * 16]; }

    // prefetch first tile: lane covers 8B of each row
    float2 px[16];
#pragma unroll
    for (int rr = 0; rr < 16; rr++) {
        int r = wbase + rr; if (r > NN - 1) r = NN - 1;
        px[rr] = *reinterpret_cast<const float2*>(&x[(size_t)r * FIN + lane * 2]);
    }

    for (int tl = 0; tl < G1T; tl++) {
        int tbase = wbase + tl * 16;
        // stage to LDS, bf16-packed, slot-swizzled (slot = u32col>>2 ^ row)
#pragma unroll
        for (int rr = 0; rr < 16; rr++) {
            uint32 v = (uint32)f2bf(px[rr].x) | ((uint32)f2bf(px[rr].y) << 16);
            int slot = (lane >> 2) ^ rr;
            xs[wv][rr][slot * 4 + (lane & 3)] = v;
        }
        __builtin_amdgcn_wave_barrier();
        // A fragments: row=lane&15, k=32t+8g+i -> u32 slot (pre-swizzle) = 4t+g
        bf16x8 a[4];
#pragma unroll
        for (int t = 0; t < 4; t++) {
            int slot = (t * 4 + g) ^ col;
            a[t] = *reinterpret_cast<const bf16x8*>(&xs[wv][col][slot * 4]);
        }
        __builtin_amdgcn_wave_barrier();
        // prefetch next tile while MFMA runs
        if (tl + 1 < G1T) {
#pragma unroll
            for (int rr = 0; rr < 16; rr++) {
                int r = tbase + 16 + rr; if (r > NN - 1) r = NN - 1;
                px[rr] = *reinterpret_cast<const float2*>(&x[(size_t)r * FIN + lane * 2]);
            }
        }
        f32x4 acc[4];
#pragma unroll
        for (int j = 0; j < 4; j++) acc[j] = (f32x4){0.f, 0.f, 0.f, 0.f};
#pragma unroll
        for (int t = 0; t < 4; t++)
#pragma unroll
            for (int j = 0; j < 4; j++)
                acc[j] = __builtin_amdgcn_mfma_f32_16x16x32_bf16(a[t], bfr[t][j], acc[j], 0, 0, 0);
        // epilogue: C layout col=lane&15 (+16j), row=tbase + 4g + reg  [m89-verified]
        float sA[4] = {0.f, 0.f, 0.f, 0.f}, sD[4] = {0.f, 0.f, 0.f, 0.f};
#pragma unroll
        for (int reg = 0; reg < 4; reg++) {
            int row = tbase + g * 4 + reg;
            bool ok = row < NN;
#pragma unroll
            for (int j = 0; j < 4; j++) {
                float v = acc[j][reg];
                if (ok) h1b[(size_t)row * C1 + col + j * 16] = f2bf(v);
                sA[reg] = fmaf(v, ats[j], sA[reg]);
                sD[reg] = fmaf(v, atd[j], sD[reg]);
            }
        }
#pragma unroll
        for (int off = 8; off; off >>= 1)
#pragma unroll
            for (int reg = 0; reg < 4; reg++) {
                sA[reg] += __shfl_xor(sA[reg], off);
                sD[reg] += __shfl_xor(sD[reg], off);
            }
        if (col == 0) {
#pragma unroll
            for (int reg = 0; reg < 4; reg++) {
                int row = tbase + g * 4 + reg;
                if (row < NN) { as1[row] = sA[reg]; ad1[row] = sD[reg]; }
            }
        }
    }
}

// ---------------- Layer 1 aggregate + bias + ixz1 + elu ----------------
__global__ __launch_bounds__(256, 8) void k_agg1(
        const int* __restrict__ rowptr, const int* __restrict__ csr_src,
        const unsigned short* __restrict__ h1b, const float* __restrict__ as1, const float* __restrict__ ad1,
        const float* __restrict__ b1,
        float* __restrict__ helu, float* __restrict__ ixz1) {
    int lane = threadIdx.x & 63;
    int node = (blockIdx.x * blockDim.x + threadIdx.x) >> 6;
    if (node >= NN) return;
    int start = rowptr[node], end = rowptr[node + 1];
    int deg = end - start;
    float adn = ad1[node];
    float out;

    if (deg <= 64) {
        // lane-parallel edge prep
        int s_l = csr_src[start + (lane < deg ? lane : 0)];
        float al = (lane < deg) ? lrelu(as1[s_l] + adn) : -1e30f;
        float m = al;
#pragma unroll
        for (int off = 32; off; off >>= 1) m = fmaxf(m, __shfl_xor(m, off));
        float wl = (lane < deg) ? expf(al - m) : 0.f;
        float den = wl;
#pragma unroll
        for (int off = 32; off; off >>= 1) den += __shfl_xor(den, off);

        // gather: 16 lanes x ushort4(8B) = one bf16 row; 4 edges in flight
        int f4 = lane & 15, g = lane >> 4;
        float4 acc = make_float4(0.f, 0.f, 0.f, 0.f);
        for (int e0 = 0; e0 < deg; e0 += 4) {
            int e = e0 + g;
            int ee = (e < deg) ? e : 0;
            float wgt = __shfl(wl, ee);
            int s = __shfl(s_l, ee);
            if (e < deg) {
                uint2 p = *reinterpret_cast<const uint2*>(&h1b[(size_t)s * C1 + f4 * 4]);
                acc.x = fmaf(wgt, bf2f_lo(p.x), acc.x);
                acc.y = fmaf(wgt, bf2f_hi(p.x), acc.y);
                acc.z = fmaf(wgt, bf2f_lo(p.y), acc.z);
                acc.w = fmaf(wgt, bf2f_hi(p.y), acc.w);
            }
        }
#pragma unroll
        for (int off = 16; off <= 32; off <<= 1) {
            acc.x += __shfl_xor(acc.x, off);
            acc.y += __shfl_xor(acc.y, off);
            acc.z += __shfl_xor(acc.z, off);
            acc.w += __shfl_xor(acc.w, off);
        }
        // transpose back: lane l owns feature l (src lane l>>2, component l&3)
        int srcl = lane >> 2;
        float t0 = __shfl(acc.x, srcl);
        float t1 = __shfl(acc.y, srcl);
        float t2 = __shfl(acc.z, srcl);
        float t3 = __shfl(acc.w, srcl);
        float t01 = (lane & 1) ? t1 : t0;
        float t23 = (lane & 1) ? t3 : t2;
        float av = (lane & 2) ? t23 : t01;
        out = av / (den + 1e-16f) + b1[lane];
    } else {
        // fallback: serial
        float m = -1e30f;
        for (int e = start + lane; e < end; e += 64) {
            int s = csr_src[e];
            m = fmaxf(m, lrelu(as1[s] + adn));
        }
#pragma unroll
        for (int off = 32; off; off >>= 1) m = fmaxf(m, __shfl_xor(m, off));
        float acc = 0.f, den = 0.f;
        for (int e = start; e < end; e++) {
            int s = csr_src[e];
            float a = lrelu(as1[s] + adn);
            float wgt = expf(a - m);
            den += wgt;
            acc += wgt * __uint_as_float(((uint32)h1b[(size_t)s * C1 + lane]) << 16);
        }
        out = acc / (den + 1e-16f) + b1[lane];
    }
    // lane-parallel epilogue (feature = lane)
    helu[(size_t)node * C1 + lane] = out > 0.f ? out : expm1f(out);
    float other = __shfl_down(out, 32);
    if (lane < 32) {
        float sd = softplusf(other) + 1e-10f;
        float kl = -logf(sd) + 0.5f * (sd * sd + out * out - 1.f);
        ixz1[(size_t)node * 32 + lane] = kl;
    }
}

// ---------------- Layer 2 GEMM: h2 = helu @ W2 (bf16 out), + attention dots ----------------
__global__ __launch_bounds__(256, 4) void k_gemm2(
        const float* __restrict__ helu, const float* __restrict__ W2,
        const float* __restrict__ attS, const float* __restrict__ attD,
        unsigned short* __restrict__ h2b, float* __restrict__ as2, float* __restrict__ ad2) {
    int lane = threadIdx.x & 63;
    int wv = threadIdx.x >> 6;
    int f = lane & 15, rg = lane >> 4;
    int n0 = (blockIdx.x * 4 + wv) * 4;
    if (n0 >= NN) return;
    float w[C1];
#pragma unroll
    for (int k = 0; k < C1; k++) w[k] = W2[k * C2 + f];
    int n = n0 + rg;
    bool valid = n < NN;
    float acc = 0.f;
    if (valid) {
        const float* xr = &helu[(size_t)n * C1];
#pragma unroll
        for (int k4 = 0; k4 < C1 / 4; k4++) {
            float4 xk = *reinterpret_cast<const float4*>(&xr[k4 * 4]);
            acc = fmaf(xk.x, w[k4 * 4 + 0], acc);
            acc = fmaf(xk.y, w[k4 * 4 + 1], acc);
            acc = fmaf(xk.z, w[k4 * 4 + 2], acc);
            acc = fmaf(xk.w, w[k4 * 4 + 3], acc);
        }
        h2b[(size_t)n * C2 + f] = f2bf(acc);
    }
    float s1 = acc * attS[f], d1 = acc * attD[f];
#pragma unroll
    for (int off = 1; off < 16; off <<= 1) {
        s1 += __shfl_xor(s1, off);
        d1 += __shfl_xor(d1, off);
    }
    if (valid && f == 0) { as2[n] = s1; ad2[n] = d1; }
}

// ---------------- Layer 2 aggregate + bias + out2 + ixz2 ----------------
__global__ __launch_bounds__(256, 8) void k_agg2(
        const int* __restrict__ rowptr, const int* __restrict__ csr_src,
        const unsigned short* __restrict__ h2b, const float* __restrict__ as2, const float* __restrict__ ad2,
        const float* __restrict__ b2,
        float* __restrict__ out2, float* __restrict__ ixz2) {
    int lane = threadIdx.x & 63;
    int node = (blockIdx.x * blockDim.x + threadIdx.x) >> 6;
    if (node >= NN) return;
    int start = rowptr[node], end = rowptr[node + 1];
    int deg = end - start;
    float adn = ad2[node];
    float out = 0.f;

    if (deg <= 64) {
        int s_l = csr_src[start + (lane < deg ? lane : 0)];
        float al = (lane < deg) ? lrelu(as2[s_l] + adn) : -1e30f;
        float m = al;
#pragma unroll
        for (int off = 32; off; off >>= 1) m = fmaxf(m, __shfl_xor(m, off));
        float wl = (lane < deg) ? expf(al - m) : 0.f;
        float den = wl;
#pragma unroll
        for (int off = 32; off; off >>= 1) den += __shfl_xor(den, off);

        // gather: 8 lanes x ushort2(4B) = one bf16 row; 8 edges in flight
        int f4 = lane & 7, g = lane >> 3;
        float2 acc = make_float2(0.f, 0.f);
        for (int e0 = 0; e0 < deg; e0 += 8) {
            int e = e0 + g;
            int ee = (e < deg) ? e : 0;
            float wgt = __shfl(wl, ee);
            int s = __shfl(s_l, ee);
            if (e < deg) {
                uint32 p = *reinterpret_cast<const uint32*>(&h2b[(size_t)s * C2 + f4 * 2]);
                acc.x = fmaf(wgt, bf2f_lo(p), acc.x);
                acc.y = fmaf(wgt, bf2f_hi(p), acc.y);
            }
        }
#pragma unroll
        for (int off = 8; off <= 32; off <<= 1) {
            acc.x += __shfl_xor(acc.x, off);
            acc.y += __shfl_xor(acc.y, off);
        }
        // transpose: lane l (<16) owns feature l (src lane l>>1, component l&1)
        int srcl = lane >> 1;
        float t0 = __shfl(acc.x, srcl);
        float t1 = __shfl(acc.y, srcl);
        float av = (lane & 1) ? t1 : t0;
        out = av / (den + 1e-16f) + b2[lane & 15];
    } else {
        int f = lane & 15, g = lane >> 4;
        float m = -1e30f;
        for (int e = start + lane; e < end; e += 64) {
            int s = csr_src[e];
            m = fmaxf(m, lrelu(as2[s] + adn));
        }
#pragma unroll
        for (int off = 32; off; off >>= 1) m = fmaxf(m, __shfl_xor(m, off));
        float acc = 0.f, den = 0.f;
        for (int e0 = start; e0 < end; e0 += 4) {
            int e = e0 + g;
            if (e < end) {
                int s = csr_src[e];
                float a = lrelu(as2[s] + adn);
                float wgt = expf(a - m);
                den += wgt;
                acc += wgt * __uint_as_float(((uint32)h2b[(size_t)s * C2 + f]) << 16);
            }
        }
        acc += __shfl_xor(acc, 16); acc += __shfl_xor(acc, 32);
        den += __shfl_xor(den, 16); den += __shfl_xor(den, 32);
        out = acc / (den + 1e-16f) + b2[f];
    }
    // lane-parallel epilogue (feature = lane for lanes 0..15)
    if (lane < 16) out2[(size_t)node * C2 + lane] = out;
    float other = __shfl_down(out, 8);
    if (lane < 8) {
        float sd = softplusf(other) + 1e-10f;
        float kl = -logf(sd) + 0.5f * (sd * sd + out * out - 1.f);
        ixz2[(size_t)node * 8 + lane] = kl;
    }
}

extern "C" void kernel_launch(void* const* d_in, const int* in_sizes, int n_in,
                              void* d_out, int out_size, void* d_ws, size_t ws_size,
                              hipStream_t stream) {
    const float* x     = (const float*)d_in[0];
    const int*   ei    = (const int*)d_in[1];
    const float* W1    = (const float*)d_in[2];
    const float* aS1   = (const float*)d_in[3];
    const float* aD1   = (const float*)d_in[4];
    const float* b1    = (const float*)d_in[5];
    const float* W2    = (const float*)d_in[6];
    const float* aS2   = (const float*)d_in[7];
    const float* aD2   = (const float*)d_in[8];
    const float* b2    = (const float*)d_in[9];

    float* out = (float*)d_out;
    float* out2 = out;                         // N*16
    float* ixz1 = out + (size_t)NN * C2;       // N*32
    float* ixz2 = ixz1 + (size_t)NN * 32;      // N*8

    char* p = (char*)d_ws;
    auto alloc = [&](size_t bytes) -> void* {
        void* r = (void*)p;
        p += (bytes + 255) & ~(size_t)255;
        return r;
    };
    int* deg     = (int*)alloc((size_t)NN * 4);
    int* cnt     = (int*)alloc((size_t)NN * 4);
    int* incl    = (int*)alloc((size_t)NN * 4);
    int* bsum    = (int*)alloc(512 * 4);
    int* boff    = (int*)alloc(512 * 4);
    int* rowptr  = (int*)alloc((size_t)(NN + 1) * 4);
    int* csr_src = (int*)alloc((size_t)ET * 4);
    unsigned short* h1b = (unsigned short*)alloc((size_t)NN * C1 * 2);
    float* as1   = (float*)alloc((size_t)NN * 4);
    float* ad1   = (float*)alloc((size_t)NN * 4);
    float* helu  = (float*)alloc((size_t)NN * C1 * 4);
    unsigned short* h2b = (unsigned short*)alloc((size_t)NN * C2 * 2);
    float* as2   = (float*)alloc((size_t)NN * 4);
    float* ad2   = (float*)alloc((size_t)NN * 4);
    (void)ws_size; (void)in_sizes; (void)n_in; (void)out_size;

    // CSR build
    k_zero<<<(NN + 255) / 256, 256, 0, stream>>>(deg, cnt);
    k_hist<<<(ET + 255) / 256, 256, 0, stream>>>(ei, deg);
    k_scan1<<<SCAN_NB, SCAN_B, 0, stream>>>(deg, incl, bsum);
    k_scan2<<<1, 64, 0, stream>>>(bsum, boff);
    k_scan3<<<(NN + 255) / 256, 256, 0, stream>>>(incl, boff, rowptr);
    k_scatter<<<(ET + 255) / 256, 256, 0, stream>>>(ei, rowptr, cnt, csr_src);

    // Layer 1
    k_gemm1<<<(NN + 4 * G1T * 16 - 1) / (4 * G1T * 16), 256, 0, stream>>>(x, W1, aS1, aD1, h1b, as1, ad1);
    k_agg1<<<(NN + 3) / 4, 256, 0, stream>>>(rowptr, csr_src, h1b, as1, ad1, b1, helu, ixz1);

    // Layer 2
    k_gemm2<<<(NN + 15) / 16, 256, 0, stream>>>(helu, W2, aS2, aD2, h2b, as2, ad2);
    k_agg2<<<(NN + 3) / 4, 256, 0, stream>>>(rowptr, csr_src, h2b, as2, ad2, b2, out2, ixz2);
}

// Round 5
// 216.015 us; speedup vs baseline: 1.6519x; 1.0614x over previous
//
#include <hip/hip_runtime.h>
#include <math.h>

#define NN 100000
#define NE 640000
#define ET (NE + NN)          // edges + self loops = 740000
#define FIN 128
#define C1 64
#define C2 16
#define NEG_SLOPE 0.2f
#define SCAN_B 1024
#define SCAN_NB ((NN + SCAN_B - 1) / SCAN_B)   // 98

typedef unsigned int uint32;
typedef __attribute__((ext_vector_type(8))) short bf16x8;
typedef __attribute__((ext_vector_type(4))) float f32x4;

static __device__ __forceinline__ float lrelu(float x) { return x > 0.f ? x : NEG_SLOPE * x; }
static __device__ __forceinline__ float softplusf(float x) {
    return fmaxf(x, 0.f) + log1pf(expf(-fabsf(x)));
}
static __device__ __forceinline__ unsigned short f2bf(float f) {   // RNE
    uint32 u = __float_as_uint(f);
    u += 0x7fffu + ((u >> 16) & 1u);
    return (unsigned short)(u >> 16);
}
static __device__ __forceinline__ float bf2f_lo(uint32 p) { return __uint_as_float(p << 16); }
static __device__ __forceinline__ float bf2f_hi(uint32 p) { return __uint_as_float(p & 0xffff0000u); }

// ---------------- CSR build ----------------
__global__ void k_zero(int* __restrict__ deg, int* __restrict__ cnt) {
    int i = blockIdx.x * blockDim.x + threadIdx.x;
    if (i < NN) { deg[i] = 0; cnt[i] = 0; }
}

__global__ void k_hist(const int* __restrict__ ei, int* __restrict__ deg) {
    int i = blockIdx.x * blockDim.x + threadIdx.x;
    if (i >= ET) return;
    int dst = (i < NE) ? ei[NE + i] : (i - NE);
    atomicAdd(&deg[dst], 1);
}

__global__ void k_scan1(const int* __restrict__ deg, int* __restrict__ incl, int* __restrict__ bsum) {
    __shared__ int s[SCAN_B];
    int ti = threadIdx.x;
    int i = blockIdx.x * SCAN_B + ti;
    int v = (i < NN) ? deg[i] : 0;
    s[ti] = v; __syncthreads();
    for (int d = 1; d < SCAN_B; d <<= 1) {
        int t = (ti >= d) ? s[ti - d] : 0;
        __syncthreads();
        s[ti] += t;
        __syncthreads();
    }
    if (i < NN) incl[i] = s[ti];
    if (ti == SCAN_B - 1) bsum[blockIdx.x] = s[ti];
}

__global__ void k_scan2(const int* __restrict__ bsum, int* __restrict__ boff) {
    if (threadIdx.x == 0 && blockIdx.x == 0) {
        int r = 0;
        for (int j = 0; j < SCAN_NB; j++) { boff[j] = r; r += bsum[j]; }
    }
}

__global__ void k_scan3(const int* __restrict__ incl, const int* __restrict__ boff, int* __restrict__ rowptr) {
    int i = blockIdx.x * blockDim.x + threadIdx.x;
    if (i < NN) rowptr[i + 1] = incl[i] + boff[i >> 10];
    if (i == 0) rowptr[0] = 0;
}

// scatter + fused per-edge alpha for layer 1 (as1/ad1 already computed by gemm1)
__global__ void k_scatter(const int* __restrict__ ei, const int* __restrict__ rowptr,
                          int* __restrict__ cnt,
                          const float* __restrict__ as1, const float* __restrict__ ad1,
                          int* __restrict__ csr_src, int* __restrict__ csr_dst,
                          float* __restrict__ alphaE) {
    int i = blockIdx.x * blockDim.x + threadIdx.x;
    if (i >= ET) return;
    int src, dst;
    if (i < NE) { src = ei[i]; dst = ei[NE + i]; }
    else        { src = i - NE; dst = src; }
    int pos = rowptr[dst] + atomicAdd(&cnt[dst], 1);
    csr_src[pos] = src;
    csr_dst[pos] = dst;
    alphaE[pos] = lrelu(as1[src] + ad1[dst]);
}

// per-edge alpha for layer 2 (after gemm2)
__global__ void k_alpha2(const int* __restrict__ csr_src, const int* __restrict__ csr_dst,
                         const float* __restrict__ as2, const float* __restrict__ ad2,
                         float* __restrict__ alphaE) {
    int i = blockIdx.x * blockDim.x + threadIdx.x;
    if (i >= ET) return;
    alphaE[i] = lrelu(as2[csr_src[i]] + ad2[csr_dst[i]]);
}

// ---------------- Layer 1 GEMM (MFMA bf16): h1 = x @ W1, + attention dots ----------------
#define G1T 2
__global__ __launch_bounds__(256, 3) void k_gemm1(
        const float* __restrict__ x, const float* __restrict__ W1,
        const float* __restrict__ attS, const float* __restrict__ attD,
        unsigned short* __restrict__ h1b, float* __restrict__ as1, float* __restrict__ ad1) {
    __shared__ uint32 xs[4][16][64];   // per-wave 16 rows x 128 bf16 (packed u32), slot-swizzled
    int lane = threadIdx.x & 63;
    int wv = threadIdx.x >> 6;
    int col = lane & 15;
    int g = lane >> 4;
    int wbase = (blockIdx.x * 4 + wv) * (G1T * 16);
    if (wbase >= NN) return;

    bf16x8 bfr[4][4];
#pragma unroll
    for (int t = 0; t < 4; t++)
#pragma unroll
        for (int j = 0; j < 4; j++) {
            int c = col + j * 16;
#pragma unroll
            for (int i = 0; i < 8; i++)
                bfr[t][j][i] = (short)f2bf(W1[(t * 32 + g * 8 + i) * C1 + c]);
        }
    float ats[4], atd[4];
#pragma unroll
    for (int j = 0; j < 4; j++) { ats[j] = attS[col + j * 16]; atd[j] = attD[col + j * 16]; }

    float2 px[16];
#pragma unroll
    for (int rr = 0; rr < 16; rr++) {
        int r = wbase + rr; if (r > NN - 1) r = NN - 1;
        px[rr] = *reinterpret_cast<const float2*>(&x[(size_t)r * FIN + lane * 2]);
    }

    for (int tl = 0; tl < G1T; tl++) {
        int tbase = wbase + tl * 16;
#pragma unroll
        for (int rr = 0; rr < 16; rr++) {
            uint32 v = (uint32)f2bf(px[rr].x) | ((uint32)f2bf(px[rr].y) << 16);
            int slot = (lane >> 2) ^ rr;
            xs[wv][rr][slot * 4 + (lane & 3)] = v;
        }
        __builtin_amdgcn_wave_barrier();
        bf16x8 a[4];
#pragma unroll
        for (int t = 0; t < 4; t++) {
            int slot = (t * 4 + g) ^ col;
            a[t] = *reinterpret_cast<const bf16x8*>(&xs[wv][col][slot * 4]);
        }
        __builtin_amdgcn_wave_barrier();
        if (tl + 1 < G1T) {
#pragma unroll
            for (int rr = 0; rr < 16; rr++) {
                int r = tbase + 16 + rr; if (r > NN - 1) r = NN - 1;
                px[rr] = *reinterpret_cast<const float2*>(&x[(size_t)r * FIN + lane * 2]);
            }
        }
        f32x4 acc[4];
#pragma unroll
        for (int j = 0; j < 4; j++) acc[j] = (f32x4){0.f, 0.f, 0.f, 0.f};
#pragma unroll
        for (int t = 0; t < 4; t++)
#pragma unroll
            for (int j = 0; j < 4; j++)
                acc[j] = __builtin_amdgcn_mfma_f32_16x16x32_bf16(a[t], bfr[t][j], acc[j], 0, 0, 0);
        float sA[4] = {0.f, 0.f, 0.f, 0.f}, sD[4] = {0.f, 0.f, 0.f, 0.f};
#pragma unroll
        for (int reg = 0; reg < 4; reg++) {
            int row = tbase + g * 4 + reg;
            bool ok = row < NN;
#pragma unroll
            for (int j = 0; j < 4; j++) {
                float v = acc[j][reg];
                if (ok) h1b[(size_t)row * C1 + col + j * 16] = f2bf(v);
                sA[reg] = fmaf(v, ats[j], sA[reg]);
                sD[reg] = fmaf(v, atd[j], sD[reg]);
            }
        }
#pragma unroll
        for (int off = 8; off; off >>= 1)
#pragma unroll
            for (int reg = 0; reg < 4; reg++) {
                sA[reg] += __shfl_xor(sA[reg], off);
                sD[reg] += __shfl_xor(sD[reg], off);
            }
        if (col == 0) {
#pragma unroll
            for (int reg = 0; reg < 4; reg++) {
                int row = tbase + g * 4 + reg;
                if (row < NN) { as1[row] = sA[reg]; ad1[row] = sD[reg]; }
            }
        }
    }
}

// ---------------- Layer 1 aggregate + bias + ixz1 + elu (bf16 out) ----------------
__global__ __launch_bounds__(256, 8) void k_agg1(
        const int* __restrict__ rowptr, const int* __restrict__ csr_src,
        const float* __restrict__ alphaE,
        const unsigned short* __restrict__ h1b, const float* __restrict__ b1,
        unsigned short* __restrict__ heb, float* __restrict__ ixz1) {
    int lane = threadIdx.x & 63;
    int node = (blockIdx.x * blockDim.x + threadIdx.x) >> 6;
    if (node >= NN) return;
    int start = rowptr[node], end = rowptr[node + 1];
    int deg = end - start;
    float out;

    if (deg <= 64) {
        int s_l = csr_src[start + (lane < deg ? lane : 0)];
        float al = (lane < deg) ? alphaE[start + lane] : -1e30f;
        float m = al;
#pragma unroll
        for (int off = 32; off; off >>= 1) m = fmaxf(m, __shfl_xor(m, off));
        float wl = (lane < deg) ? expf(al - m) : 0.f;
        float den = wl;
#pragma unroll
        for (int off = 32; off; off >>= 1) den += __shfl_xor(den, off);
        wl *= 1.f / (den + 1e-16f);        // pre-normalized weight

        int f4 = lane & 15, g = lane >> 4;
        float4 acc = make_float4(0.f, 0.f, 0.f, 0.f);
        for (int e0 = 0; e0 < deg; e0 += 4) {
            int e = e0 + g;
            int ee = (e < deg) ? e : 0;
            float wgt = __shfl(wl, ee);
            int s = __shfl(s_l, ee);
            if (e < deg) {
                uint2 p = *reinterpret_cast<const uint2*>(&h1b[(size_t)s * C1 + f4 * 4]);
                acc.x = fmaf(wgt, bf2f_lo(p.x), acc.x);
                acc.y = fmaf(wgt, bf2f_hi(p.x), acc.y);
                acc.z = fmaf(wgt, bf2f_lo(p.y), acc.z);
                acc.w = fmaf(wgt, bf2f_hi(p.y), acc.w);
            }
        }
#pragma unroll
        for (int off = 16; off <= 32; off <<= 1) {
            acc.x += __shfl_xor(acc.x, off);
            acc.y += __shfl_xor(acc.y, off);
            acc.z += __shfl_xor(acc.z, off);
            acc.w += __shfl_xor(acc.w, off);
        }
        int srcl = lane >> 2;
        float t0 = __shfl(acc.x, srcl);
        float t1 = __shfl(acc.y, srcl);
        float t2 = __shfl(acc.z, srcl);
        float t3 = __shfl(acc.w, srcl);
        float t01 = (lane & 1) ? t1 : t0;
        float t23 = (lane & 1) ? t3 : t2;
        float av = (lane & 2) ? t23 : t01;
        out = av + b1[lane];
    } else {
        float m = -1e30f;
        for (int e = start + lane; e < end; e += 64) m = fmaxf(m, alphaE[e]);
#pragma unroll
        for (int off = 32; off; off >>= 1) m = fmaxf(m, __shfl_xor(m, off));
        float acc = 0.f, den = 0.f;
        for (int e = start; e < end; e++) {
            int s = csr_src[e];
            float wgt = expf(alphaE[e] - m);
            den += wgt;
            acc += wgt * __uint_as_float(((uint32)h1b[(size_t)s * C1 + lane]) << 16);
        }
        out = acc / (den + 1e-16f) + b1[lane];
    }
    float el = out > 0.f ? out : expm1f(out);
    heb[(size_t)node * C1 + lane] = f2bf(el);
    float other = __shfl_down(out, 32);
    if (lane < 32) {
        float sd = softplusf(other) + 1e-10f;
        float kl = -logf(sd) + 0.5f * (sd * sd + out * out - 1.f);
        ixz1[(size_t)node * 32 + lane] = kl;
    }
}

// ---------------- Layer 2 GEMM (MFMA bf16): h2 = elu(out1) @ W2, + attention dots ----------------
#define G2T 4
__global__ __launch_bounds__(256, 4) void k_gemm2(
        const unsigned short* __restrict__ heb, const float* __restrict__ W2,
        const float* __restrict__ attS, const float* __restrict__ attD,
        unsigned short* __restrict__ h2b, float* __restrict__ as2, float* __restrict__ ad2) {
    int lane = threadIdx.x & 63;
    int wv = threadIdx.x >> 6;
    int col = lane & 15, g = lane >> 4;
    int wbase = (blockIdx.x * 4 + wv) * (G2T * 16);
    if (wbase >= NN) return;
    bf16x8 bfr[2];
#pragma unroll
    for (int t = 0; t < 2; t++)
#pragma unroll
        for (int i = 0; i < 8; i++)
            bfr[t][i] = (short)f2bf(W2[(t * 32 + g * 8 + i) * C2 + col]);
    float ats = attS[col], atd = attD[col];
#pragma unroll
    for (int tl = 0; tl < G2T; tl++) {
        int tbase = wbase + tl * 16;
        if (tbase >= NN) break;
        int arow = tbase + col; if (arow > NN - 1) arow = NN - 1;
        // A-frag direct from global: rows are contiguous 128B, 16B/lane
        bf16x8 a0 = *reinterpret_cast<const bf16x8*>(&heb[(size_t)arow * C1 + g * 8]);
        bf16x8 a1 = *reinterpret_cast<const bf16x8*>(&heb[(size_t)arow * C1 + 32 + g * 8]);
        f32x4 acc = (f32x4){0.f, 0.f, 0.f, 0.f};
        acc = __builtin_amdgcn_mfma_f32_16x16x32_bf16(a0, bfr[0], acc, 0, 0, 0);
        acc = __builtin_amdgcn_mfma_f32_16x16x32_bf16(a1, bfr[1], acc, 0, 0, 0);
        float sA[4], sD[4];
#pragma unroll
        for (int reg = 0; reg < 4; reg++) {
            int row = tbase + g * 4 + reg;
            if (row < NN) h2b[(size_t)row * C2 + col] = f2bf(acc[reg]);
            sA[reg] = acc[reg] * ats;
            sD[reg] = acc[reg] * atd;
        }
#pragma unroll
        for (int off = 8; off; off >>= 1)
#pragma unroll
            for (int reg = 0; reg < 4; reg++) {
                sA[reg] += __shfl_xor(sA[reg], off);
                sD[reg] += __shfl_xor(sD[reg], off);
            }
        if (col == 0) {
#pragma unroll
            for (int reg = 0; reg < 4; reg++) {
                int row = tbase + g * 4 + reg;
                if (row < NN) { as2[row] = sA[reg]; ad2[row] = sD[reg]; }
            }
        }
    }
}

// ---------------- Layer 2 aggregate + bias + out2 + ixz2 ----------------
__global__ __launch_bounds__(256, 8) void k_agg2(
        const int* __restrict__ rowptr, const int* __restrict__ csr_src,
        const float* __restrict__ alphaE,
        const unsigned short* __restrict__ h2b, const float* __restrict__ b2,
        float* __restrict__ out2, float* __restrict__ ixz2) {
    int lane = threadIdx.x & 63;
    int node = (blockIdx.x * blockDim.x + threadIdx.x) >> 6;
    if (node >= NN) return;
    int start = rowptr[node], end = rowptr[node + 1];
    int deg = end - start;
    float out = 0.f;

    if (deg <= 64) {
        int s_l = csr_src[start + (lane < deg ? lane : 0)];
        float al = (lane < deg) ? alphaE[start + lane] : -1e30f;
        float m = al;
#pragma unroll
        for (int off = 32; off; off >>= 1) m = fmaxf(m, __shfl_xor(m, off));
        float wl = (lane < deg) ? expf(al - m) : 0.f;
        float den = wl;
#pragma unroll
        for (int off = 32; off; off >>= 1) den += __shfl_xor(den, off);
        wl *= 1.f / (den + 1e-16f);

        int f4 = lane & 7, g = lane >> 3;
        float2 acc = make_float2(0.f, 0.f);
        for (int e0 = 0; e0 < deg; e0 += 8) {
            int e = e0 + g;
            int ee = (e < deg) ? e : 0;
            float wgt = __shfl(wl, ee);
            int s = __shfl(s_l, ee);
            if (e < deg) {
                uint32 p = *reinterpret_cast<const uint32*>(&h2b[(size_t)s * C2 + f4 * 2]);
                acc.x = fmaf(wgt, bf2f_lo(p), acc.x);
                acc.y = fmaf(wgt, bf2f_hi(p), acc.y);
            }
        }
#pragma unroll
        for (int off = 8; off <= 32; off <<= 1) {
            acc.x += __shfl_xor(acc.x, off);
            acc.y += __shfl_xor(acc.y, off);
        }
        int srcl = lane >> 1;
        float t0 = __shfl(acc.x, srcl);
        float t1 = __shfl(acc.y, srcl);
        float av = (lane & 1) ? t1 : t0;
        out = av + b2[lane & 15];
    } else {
        int f = lane & 15, g = lane >> 4;
        float m = -1e30f;
        for (int e = start + lane; e < end; e += 64) m = fmaxf(m, alphaE[e]);
#pragma unroll
        for (int off = 32; off; off >>= 1) m = fmaxf(m, __shfl_xor(m, off));
        float acc = 0.f, den = 0.f;
        for (int e0 = start; e0 < end; e0 += 4) {
            int e = e0 + g;
            if (e < end) {
                int s = csr_src[e];
                float wgt = expf(alphaE[e] - m);
                den += wgt;
                acc += wgt * __uint_as_float(((uint32)h2b[(size_t)s * C2 + f]) << 16);
            }
        }
        acc += __shfl_xor(acc, 16); acc += __shfl_xor(acc, 32);
        den += __shfl_xor(den, 16); den += __shfl_xor(den, 32);
        out = acc / (den + 1e-16f) + b2[f];
    }
    if (lane < 16) out2[(size_t)node * C2 + lane] = out;
    float other = __shfl_down(out, 8);
    if (lane < 8) {
        float sd = softplusf(other) + 1e-10f;
        float kl = -logf(sd) + 0.5f * (sd * sd + out * out - 1.f);
        ixz2[(size_t)node * 8 + lane] = kl;
    }
}

extern "C" void kernel_launch(void* const* d_in, const int* in_sizes, int n_in,
                              void* d_out, int out_size, void* d_ws, size_t ws_size,
                              hipStream_t stream) {
    const float* x     = (const float*)d_in[0];
    const int*   ei    = (const int*)d_in[1];
    const float* W1    = (const float*)d_in[2];
    const float* aS1   = (const float*)d_in[3];
    const float* aD1   = (const float*)d_in[4];
    const float* b1    = (const float*)d_in[5];
    const float* W2    = (const float*)d_in[6];
    const float* aS2   = (const float*)d_in[7];
    const float* aD2   = (const float*)d_in[8];
    const float* b2    = (const float*)d_in[9];

    float* out = (float*)d_out;
    float* out2 = out;                         // N*16
    float* ixz1 = out + (size_t)NN * C2;       // N*32
    float* ixz2 = ixz1 + (size_t)NN * 32;      // N*8

    char* p = (char*)d_ws;
    auto alloc = [&](size_t bytes) -> void* {
        void* r = (void*)p;
        p += (bytes + 255) & ~(size_t)255;
        return r;
    };
    int* deg     = (int*)alloc((size_t)NN * 4);
    int* cnt     = (int*)alloc((size_t)NN * 4);
    int* incl    = (int*)alloc((size_t)NN * 4);
    int* bsum    = (int*)alloc(512 * 4);
    int* boff    = (int*)alloc(512 * 4);
    int* rowptr  = (int*)alloc((size_t)(NN + 1) * 4);
    int* csr_src = (int*)alloc((size_t)ET * 4);
    int* csr_dst = (int*)alloc((size_t)ET * 4);
    float* alphaE = (float*)alloc((size_t)ET * 4);
    unsigned short* h1b = (unsigned short*)alloc((size_t)NN * C1 * 2);
    float* as1   = (float*)alloc((size_t)NN * 4);
    float* ad1   = (float*)alloc((size_t)NN * 4);
    unsigned short* heb = (unsigned short*)alloc((size_t)NN * C1 * 2);
    unsigned short* h2b = (unsigned short*)alloc((size_t)NN * C2 * 2);
    float* as2   = (float*)alloc((size_t)NN * 4);
    float* ad2   = (float*)alloc((size_t)NN * 4);
    (void)ws_size; (void)in_sizes; (void)n_in; (void)out_size;

    // Layer-1 GEMM first (as1/ad1 feed the fused scatter+alpha)
    k_gemm1<<<(NN + 4 * G1T * 16 - 1) / (4 * G1T * 16), 256, 0, stream>>>(x, W1, aS1, aD1, h1b, as1, ad1);

    // CSR build + fused alpha1
    k_zero<<<(NN + 255) / 256, 256, 0, stream>>>(deg, cnt);
    k_hist<<<(ET + 255) / 256, 256, 0, stream>>>(ei, deg);
    k_scan1<<<SCAN_NB, SCAN_B, 0, stream>>>(deg, incl, bsum);
    k_scan2<<<1, 64, 0, stream>>>(bsum, boff);
    k_scan3<<<(NN + 255) / 256, 256, 0, stream>>>(incl, boff, rowptr);
    k_scatter<<<(ET + 255) / 256, 256, 0, stream>>>(ei, rowptr, cnt, as1, ad1, csr_src, csr_dst, alphaE);

    // Layer 1 aggregate
    k_agg1<<<(NN + 3) / 4, 256, 0, stream>>>(rowptr, csr_src, alphaE, h1b, b1, heb, ixz1);

    // Layer 2
    k_gemm2<<<(NN + 4 * G2T * 16 - 1) / (4 * G2T * 16), 256, 0, stream>>>(heb, W2, aS2, aD2, h2b, as2, ad2);
    k_alpha2<<<(ET + 255) / 256, 256, 0, stream>>>(csr_src, csr_dst, as2, ad2, alphaE);
    k_agg2<<<(NN + 3) / 4, 256, 0, stream>>>(rowptr, csr_src, alphaE, h2b, b2, out2, ixz2);
}

// Round 6
// 182.335 us; speedup vs baseline: 1.9570x; 1.1847x over previous
//
#include <hip/hip_runtime.h>
#include <math.h>

#define NN 100000
#define NE 640000
#define ET (NE + NN)          // edges + self loops = 740000
#define FIN 128
#define C1 64
#define C2 16
#define NEG_SLOPE 0.2f
#define SCAN_B 1024
#define SCAN_NB ((NN + SCAN_B - 1) / SCAN_B)   // 98

typedef unsigned int uint32;
typedef __attribute__((ext_vector_type(8))) short bf16x8;
typedef __attribute__((ext_vector_type(4))) float f32x4;

static __device__ __forceinline__ float lrelu(float x) { return x > 0.f ? x : NEG_SLOPE * x; }
static __device__ __forceinline__ float softplusf(float x) {
    return fmaxf(x, 0.f) + log1pf(expf(-fabsf(x)));
}
static __device__ __forceinline__ unsigned short f2bf(float f) {   // RNE
    uint32 u = __float_as_uint(f);
    u += 0x7fffu + ((u >> 16) & 1u);
    return (unsigned short)(u >> 16);
}
static __device__ __forceinline__ float bf2f_lo(uint32 p) { return __uint_as_float(p << 16); }
static __device__ __forceinline__ float bf2f_hi(uint32 p) { return __uint_as_float(p & 0xffff0000u); }

// ---------------- CSR build ----------------
__global__ void k_zero(int* __restrict__ deg, int* __restrict__ cnt) {
    int i = blockIdx.x * blockDim.x + threadIdx.x;
    if (i < NN) { deg[i] = 0; cnt[i] = 0; }
}

__global__ void k_hist(const int* __restrict__ ei, int* __restrict__ deg) {
    int i = blockIdx.x * blockDim.x + threadIdx.x;
    if (i >= ET) return;
    int dst = (i < NE) ? ei[NE + i] : (i - NE);
    atomicAdd(&deg[dst], 1);
}

__global__ void k_scan1(const int* __restrict__ deg, int* __restrict__ incl, int* __restrict__ bsum) {
    __shared__ int s[SCAN_B];
    int ti = threadIdx.x;
    int i = blockIdx.x * SCAN_B + ti;
    int v = (i < NN) ? deg[i] : 0;
    s[ti] = v; __syncthreads();
    for (int d = 1; d < SCAN_B; d <<= 1) {
        int t = (ti >= d) ? s[ti - d] : 0;
        __syncthreads();
        s[ti] += t;
        __syncthreads();
    }
    if (i < NN) incl[i] = s[ti];
    if (ti == SCAN_B - 1) bsum[blockIdx.x] = s[ti];
}

__global__ void k_scan2(const int* __restrict__ bsum, int* __restrict__ boff) {
    if (threadIdx.x == 0 && blockIdx.x == 0) {
        int r = 0;
        for (int j = 0; j < SCAN_NB; j++) { boff[j] = r; r += bsum[j]; }
    }
}

__global__ void k_scan3(const int* __restrict__ incl, const int* __restrict__ boff, int* __restrict__ rowptr) {
    int i = blockIdx.x * blockDim.x + threadIdx.x;
    if (i < NN) rowptr[i + 1] = incl[i] + boff[i >> 10];
    if (i == 0) rowptr[0] = 0;
}

__global__ void k_scatter(const int* __restrict__ ei, const int* __restrict__ rowptr,
                          int* __restrict__ cnt, int* __restrict__ csr_src) {
    int i = blockIdx.x * blockDim.x + threadIdx.x;
    if (i >= ET) return;
    int src, dst;
    if (i < NE) { src = ei[i]; dst = ei[NE + i]; }
    else        { src = i - NE; dst = src; }
    int pos = rowptr[dst] + atomicAdd(&cnt[dst], 1);
    csr_src[pos] = src;
}

// ---------------- Layer 1 GEMM (MFMA bf16): h1 = x @ W1, + attention dots ----------------
#define G1T 2
__global__ __launch_bounds__(256, 3) void k_gemm1(
        const float* __restrict__ x, const float* __restrict__ W1,
        const float* __restrict__ attS, const float* __restrict__ attD,
        unsigned short* __restrict__ h1b, float* __restrict__ as1, float* __restrict__ ad1) {
    __shared__ uint32 xs[4][16][64];   // per-wave 16 rows x 128 bf16 (packed u32), slot-swizzled
    int lane = threadIdx.x & 63;
    int wv = threadIdx.x >> 6;
    int col = lane & 15;
    int g = lane >> 4;
    int wbase = (blockIdx.x * 4 + wv) * (G1T * 16);
    if (wbase >= NN) return;

    bf16x8 bfr[4][4];
#pragma unroll
    for (int t = 0; t < 4; t++)
#pragma unroll
        for (int j = 0; j < 4; j++) {
            int c = col + j * 16;
#pragma unroll
            for (int i = 0; i < 8; i++)
                bfr[t][j][i] = (short)f2bf(W1[(t * 32 + g * 8 + i) * C1 + c]);
        }
    float ats[4], atd[4];
#pragma unroll
    for (int j = 0; j < 4; j++) { ats[j] = attS[col + j * 16]; atd[j] = attD[col + j * 16]; }

    float2 px[16];
#pragma unroll
    for (int rr = 0; rr < 16; rr++) {
        int r = wbase + rr; if (r > NN - 1) r = NN - 1;
        px[rr] = *reinterpret_cast<const float2*>(&x[(size_t)r * FIN + lane * 2]);
    }

    for (int tl = 0; tl < G1T; tl++) {
        int tbase = wbase + tl * 16;
#pragma unroll
        for (int rr = 0; rr < 16; rr++) {
            uint32 v = (uint32)f2bf(px[rr].x) | ((uint32)f2bf(px[rr].y) << 16);
            int slot = (lane >> 2) ^ rr;
            xs[wv][rr][slot * 4 + (lane & 3)] = v;
        }
        __builtin_amdgcn_wave_barrier();
        bf16x8 a[4];
#pragma unroll
        for (int t = 0; t < 4; t++) {
            int slot = (t * 4 + g) ^ col;
            a[t] = *reinterpret_cast<const bf16x8*>(&xs[wv][col][slot * 4]);
        }
        __builtin_amdgcn_wave_barrier();
        if (tl + 1 < G1T) {
#pragma unroll
            for (int rr = 0; rr < 16; rr++) {
                int r = tbase + 16 + rr; if (r > NN - 1) r = NN - 1;
                px[rr] = *reinterpret_cast<const float2*>(&x[(size_t)r * FIN + lane * 2]);
            }
        }
        f32x4 acc[4];
#pragma unroll
        for (int j = 0; j < 4; j++) acc[j] = (f32x4){0.f, 0.f, 0.f, 0.f};
#pragma unroll
        for (int t = 0; t < 4; t++)
#pragma unroll
            for (int j = 0; j < 4; j++)
                acc[j] = __builtin_amdgcn_mfma_f32_16x16x32_bf16(a[t], bfr[t][j], acc[j], 0, 0, 0);
        float sA[4] = {0.f, 0.f, 0.f, 0.f}, sD[4] = {0.f, 0.f, 0.f, 0.f};
#pragma unroll
        for (int reg = 0; reg < 4; reg++) {
            int row = tbase + g * 4 + reg;
            bool ok = row < NN;
#pragma unroll
            for (int j = 0; j < 4; j++) {
                float v = acc[j][reg];
                if (ok) h1b[(size_t)row * C1 + col + j * 16] = f2bf(v);
                sA[reg] = fmaf(v, ats[j], sA[reg]);
                sD[reg] = fmaf(v, atd[j], sD[reg]);
            }
        }
#pragma unroll
        for (int off = 8; off; off >>= 1)
#pragma unroll
            for (int reg = 0; reg < 4; reg++) {
                sA[reg] += __shfl_xor(sA[reg], off);
                sD[reg] += __shfl_xor(sD[reg], off);
            }
        if (col == 0) {
#pragma unroll
            for (int reg = 0; reg < 4; reg++) {
                int row = tbase + g * 4 + reg;
                if (row < NN) { as1[row] = sA[reg]; ad1[row] = sD[reg]; }
            }
        }
    }
}

// ---------------- Layer 1 aggregate: 4 nodes/wave, 16 lanes/node ----------------
__global__ __launch_bounds__(256, 8) void k_agg1(
        const int* __restrict__ rowptr, const int* __restrict__ csr_src,
        const float* __restrict__ as1, const float* __restrict__ ad1,
        const unsigned short* __restrict__ h1b, const float* __restrict__ b1,
        unsigned short* __restrict__ heb, float* __restrict__ ixz1) {
    int lane = threadIdx.x & 63;
    int wid = (blockIdx.x * blockDim.x + threadIdx.x) >> 6;
    int grp = lane >> 4, gl = lane & 15;
    int gbase = grp << 4;
    int node = wid * 4 + grp;
    if (node >= NN) return;
    int start = rowptr[node], end = rowptr[node + 1];
    int deg = end - start;
    float adn = ad1[node];
    float4 o;

    if (deg <= 16) {
        int e = start + (gl < deg ? gl : 0);
        int s_l = csr_src[e];
        float al = (gl < deg) ? lrelu(as1[s_l] + adn) : -1e30f;
        float m = al;
#pragma unroll
        for (int off = 8; off; off >>= 1) m = fmaxf(m, __shfl_xor(m, off));
        float wl = (gl < deg) ? expf(al - m) : 0.f;
        float den = wl;
#pragma unroll
        for (int off = 8; off; off >>= 1) den += __shfl_xor(den, off);
        wl *= 1.f / (den + 1e-16f);
        float4 acc = make_float4(0.f, 0.f, 0.f, 0.f);
        for (int e0 = 0; e0 < deg; e0++) {
            float wgt = __shfl(wl, gbase | e0);
            int s = __shfl(s_l, gbase | e0);
            uint2 p = *reinterpret_cast<const uint2*>(&h1b[(size_t)s * C1 + gl * 4]);
            acc.x = fmaf(wgt, bf2f_lo(p.x), acc.x);
            acc.y = fmaf(wgt, bf2f_hi(p.x), acc.y);
            acc.z = fmaf(wgt, bf2f_lo(p.y), acc.z);
            acc.w = fmaf(wgt, bf2f_hi(p.y), acc.w);
        }
        o = acc;
    } else {
        // rare: deg > 16 (~0.06% of nodes)
        float m = -1e30f;
        for (int e = start + gl; e < end; e += 16) m = fmaxf(m, lrelu(as1[csr_src[e]] + adn));
#pragma unroll
        for (int off = 8; off; off >>= 1) m = fmaxf(m, __shfl_xor(m, off));
        float den = 0.f;
        for (int e = start + gl; e < end; e += 16) den += expf(lrelu(as1[csr_src[e]] + adn) - m);
#pragma unroll
        for (int off = 8; off; off >>= 1) den += __shfl_xor(den, off);
        float inv = 1.f / (den + 1e-16f);
        float4 acc = make_float4(0.f, 0.f, 0.f, 0.f);
        for (int e = start; e < end; e++) {
            int s = csr_src[e];
            float wgt = expf(lrelu(as1[s] + adn) - m) * inv;
            uint2 p = *reinterpret_cast<const uint2*>(&h1b[(size_t)s * C1 + gl * 4]);
            acc.x = fmaf(wgt, bf2f_lo(p.x), acc.x);
            acc.y = fmaf(wgt, bf2f_hi(p.x), acc.y);
            acc.z = fmaf(wgt, bf2f_lo(p.y), acc.z);
            acc.w = fmaf(wgt, bf2f_hi(p.y), acc.w);
        }
        o = acc;
    }
    float4 bv = *reinterpret_cast<const float4*>(&b1[gl * 4]);
    o.x += bv.x; o.y += bv.y; o.z += bv.z; o.w += bv.w;
    float4 he;
    he.x = o.x > 0.f ? o.x : expm1f(o.x);
    he.y = o.y > 0.f ? o.y : expm1f(o.y);
    he.z = o.z > 0.f ? o.z : expm1f(o.z);
    he.w = o.w > 0.f ? o.w : expm1f(o.w);
    uint2 hw;
    hw.x = (uint32)f2bf(he.x) | ((uint32)f2bf(he.y) << 16);
    hw.y = (uint32)f2bf(he.z) | ((uint32)f2bf(he.w) << 16);
    *reinterpret_cast<uint2*>(&heb[(size_t)node * C1 + gl * 4]) = hw;
    float4 oth;
    oth.x = __shfl_down(o.x, 8);
    oth.y = __shfl_down(o.y, 8);
    oth.z = __shfl_down(o.z, 8);
    oth.w = __shfl_down(o.w, 8);
    if (gl < 8) {
        float4 kl; float sd;
        sd = softplusf(oth.x) + 1e-10f; kl.x = -logf(sd) + 0.5f * (sd * sd + o.x * o.x - 1.f);
        sd = softplusf(oth.y) + 1e-10f; kl.y = -logf(sd) + 0.5f * (sd * sd + o.y * o.y - 1.f);
        sd = softplusf(oth.z) + 1e-10f; kl.z = -logf(sd) + 0.5f * (sd * sd + o.z * o.z - 1.f);
        sd = softplusf(oth.w) + 1e-10f; kl.w = -logf(sd) + 0.5f * (sd * sd + o.w * o.w - 1.f);
        *reinterpret_cast<float4*>(&ixz1[(size_t)node * 32 + gl * 4]) = kl;
    }
}

// ---------------- Layer 2 GEMM (MFMA bf16): h2 = elu(out1) @ W2, + attention dots ----------------
#define G2T 4
__global__ __launch_bounds__(256, 4) void k_gemm2(
        const unsigned short* __restrict__ heb, const float* __restrict__ W2,
        const float* __restrict__ attS, const float* __restrict__ attD,
        unsigned short* __restrict__ h2b, float* __restrict__ as2, float* __restrict__ ad2) {
    int lane = threadIdx.x & 63;
    int wv = threadIdx.x >> 6;
    int col = lane & 15, g = lane >> 4;
    int wbase = (blockIdx.x * 4 + wv) * (G2T * 16);
    if (wbase >= NN) return;
    bf16x8 bfr[2];
#pragma unroll
    for (int t = 0; t < 2; t++)
#pragma unroll
        for (int i = 0; i < 8; i++)
            bfr[t][i] = (short)f2bf(W2[(t * 32 + g * 8 + i) * C2 + col]);
    float ats = attS[col], atd = attD[col];
#pragma unroll
    for (int tl = 0; tl < G2T; tl++) {
        int tbase = wbase + tl * 16;
        if (tbase >= NN) break;
        int arow = tbase + col; if (arow > NN - 1) arow = NN - 1;
        bf16x8 a0 = *reinterpret_cast<const bf16x8*>(&heb[(size_t)arow * C1 + g * 8]);
        bf16x8 a1 = *reinterpret_cast<const bf16x8*>(&heb[(size_t)arow * C1 + 32 + g * 8]);
        f32x4 acc = (f32x4){0.f, 0.f, 0.f, 0.f};
        acc = __builtin_amdgcn_mfma_f32_16x16x32_bf16(a0, bfr[0], acc, 0, 0, 0);
        acc = __builtin_amdgcn_mfma_f32_16x16x32_bf16(a1, bfr[1], acc, 0, 0, 0);
        float sA[4], sD[4];
#pragma unroll
        for (int reg = 0; reg < 4; reg++) {
            int row = tbase + g * 4 + reg;
            if (row < NN) h2b[(size_t)row * C2 + col] = f2bf(acc[reg]);
            sA[reg] = acc[reg] * ats;
            sD[reg] = acc[reg] * atd;
        }
#pragma unroll
        for (int off = 8; off; off >>= 1)
#pragma unroll
            for (int reg = 0; reg < 4; reg++) {
                sA[reg] += __shfl_xor(sA[reg], off);
                sD[reg] += __shfl_xor(sD[reg], off);
            }
        if (col == 0) {
#pragma unroll
            for (int reg = 0; reg < 4; reg++) {
                int row = tbase + g * 4 + reg;
                if (row < NN) { as2[row] = sA[reg]; ad2[row] = sD[reg]; }
            }
        }
    }
}

// ---------------- Layer 2 aggregate: 4 nodes/wave, 16 lanes/node ----------------
__global__ __launch_bounds__(256, 8) void k_agg2(
        const int* __restrict__ rowptr, const int* __restrict__ csr_src,
        const float* __restrict__ as2, const float* __restrict__ ad2,
        const unsigned short* __restrict__ h2b, const float* __restrict__ b2,
        float* __restrict__ out2, float* __restrict__ ixz2) {
    int lane = threadIdx.x & 63;
    int wid = (blockIdx.x * blockDim.x + threadIdx.x) >> 6;
    int grp = lane >> 4, gl = lane & 15;
    int gbase = grp << 4;
    int node = wid * 4 + grp;
    if (node >= NN) return;
    int start = rowptr[node], end = rowptr[node + 1];
    int deg = end - start;
    float adn = ad2[node];
    float out;

    if (deg <= 16) {
        int e = start + (gl < deg ? gl : 0);
        int s_l = csr_src[e];
        float al = (gl < deg) ? lrelu(as2[s_l] + adn) : -1e30f;
        float m = al;
#pragma unroll
        for (int off = 8; off; off >>= 1) m = fmaxf(m, __shfl_xor(m, off));
        float wl = (gl < deg) ? expf(al - m) : 0.f;
        float den = wl;
#pragma unroll
        for (int off = 8; off; off >>= 1) den += __shfl_xor(den, off);
        wl *= 1.f / (den + 1e-16f);
        // 4 lanes x 4 features, 4 edges in flight
        int f4 = gl & 3, g = gl >> 2;
        float4 acc = make_float4(0.f, 0.f, 0.f, 0.f);
        for (int e0 = 0; e0 < deg; e0 += 4) {
            int e2 = e0 + g;
            int ee = (e2 < deg) ? e2 : 0;
            float wgt = __shfl(wl, gbase | ee);
            int s = __shfl(s_l, gbase | ee);
            if (e2 < deg) {
                uint2 p = *reinterpret_cast<const uint2*>(&h2b[(size_t)s * C2 + f4 * 4]);
                acc.x = fmaf(wgt, bf2f_lo(p.x), acc.x);
                acc.y = fmaf(wgt, bf2f_hi(p.x), acc.y);
                acc.z = fmaf(wgt, bf2f_lo(p.y), acc.z);
                acc.w = fmaf(wgt, bf2f_hi(p.y), acc.w);
            }
        }
#pragma unroll
        for (int off = 4; off <= 8; off <<= 1) {
            acc.x += __shfl_xor(acc.x, off);
            acc.y += __shfl_xor(acc.y, off);
            acc.z += __shfl_xor(acc.z, off);
            acc.w += __shfl_xor(acc.w, off);
        }
        // transpose: lane gl owns feature gl (src lane gbase|(gl>>2), comp gl&3)
        int srcl = gbase | (gl >> 2);
        float t0 = __shfl(acc.x, srcl);
        float t1 = __shfl(acc.y, srcl);
        float t2 = __shfl(acc.z, srcl);
        float t3 = __shfl(acc.w, srcl);
        float t01 = (gl & 1) ? t1 : t0;
        float t23 = (gl & 1) ? t3 : t2;
        out = (gl & 2) ? t23 : t01;
    } else {
        // rare: deg > 16; lane gl owns feature gl
        float m = -1e30f;
        for (int e = start + gl; e < end; e += 16) m = fmaxf(m, lrelu(as2[csr_src[e]] + adn));
#pragma unroll
        for (int off = 8; off; off >>= 1) m = fmaxf(m, __shfl_xor(m, off));
        float den = 0.f;
        for (int e = start + gl; e < end; e += 16) den += expf(lrelu(as2[csr_src[e]] + adn) - m);
#pragma unroll
        for (int off = 8; off; off >>= 1) den += __shfl_xor(den, off);
        float inv = 1.f / (den + 1e-16f);
        float acc = 0.f;
        for (int e = start; e < end; e++) {
            int s = csr_src[e];
            float wgt = expf(lrelu(as2[s] + adn) - m) * inv;
            acc = fmaf(wgt, __uint_as_float(((uint32)h2b[(size_t)s * C2 + gl]) << 16), acc);
        }
        out = acc;
    }
    out += b2[gl];
    out2[(size_t)node * C2 + gl] = out;
    float other = __shfl_down(out, 8);
    if (gl < 8) {
        float sd = softplusf(other) + 1e-10f;
        float kl = -logf(sd) + 0.5f * (sd * sd + out * out - 1.f);
        ixz2[(size_t)node * 8 + gl] = kl;
    }
}

extern "C" void kernel_launch(void* const* d_in, const int* in_sizes, int n_in,
                              void* d_out, int out_size, void* d_ws, size_t ws_size,
                              hipStream_t stream) {
    const float* x     = (const float*)d_in[0];
    const int*   ei    = (const int*)d_in[1];
    const float* W1    = (const float*)d_in[2];
    const float* aS1   = (const float*)d_in[3];
    const float* aD1   = (const float*)d_in[4];
    const float* b1    = (const float*)d_in[5];
    const float* W2    = (const float*)d_in[6];
    const float* aS2   = (const float*)d_in[7];
    const float* aD2   = (const float*)d_in[8];
    const float* b2    = (const float*)d_in[9];

    float* out = (float*)d_out;
    float* out2 = out;                         // N*16
    float* ixz1 = out + (size_t)NN * C2;       // N*32
    float* ixz2 = ixz1 + (size_t)NN * 32;      // N*8

    char* p = (char*)d_ws;
    auto alloc = [&](size_t bytes) -> void* {
        void* r = (void*)p;
        p += (bytes + 255) & ~(size_t)255;
        return r;
    };
    int* deg     = (int*)alloc((size_t)NN * 4);
    int* cnt     = (int*)alloc((size_t)NN * 4);
    int* incl    = (int*)alloc((size_t)NN * 4);
    int* bsum    = (int*)alloc(512 * 4);
    int* boff    = (int*)alloc(512 * 4);
    int* rowptr  = (int*)alloc((size_t)(NN + 1) * 4);
    int* csr_src = (int*)alloc((size_t)ET * 4);
    unsigned short* h1b = (unsigned short*)alloc((size_t)NN * C1 * 2);
    float* as1   = (float*)alloc((size_t)NN * 4);
    float* ad1   = (float*)alloc((size_t)NN * 4);
    unsigned short* heb = (unsigned short*)alloc((size_t)NN * C1 * 2);
    unsigned short* h2b = (unsigned short*)alloc((size_t)NN * C2 * 2);
    float* as2   = (float*)alloc((size_t)NN * 4);
    float* ad2   = (float*)alloc((size_t)NN * 4);
    (void)ws_size; (void)in_sizes; (void)n_in; (void)out_size;

    // Layer-1 GEMM (independent of CSR build)
    k_gemm1<<<(NN + 4 * G1T * 16 - 1) / (4 * G1T * 16), 256, 0, stream>>>(x, W1, aS1, aD1, h1b, as1, ad1);

    // CSR build
    k_zero<<<(NN + 255) / 256, 256, 0, stream>>>(deg, cnt);
    k_hist<<<(ET + 255) / 256, 256, 0, stream>>>(ei, deg);
    k_scan1<<<SCAN_NB, SCAN_B, 0, stream>>>(deg, incl, bsum);
    k_scan2<<<1, 64, 0, stream>>>(bsum, boff);
    k_scan3<<<(NN + 255) / 256, 256, 0, stream>>>(incl, boff, rowptr);
    k_scatter<<<(ET + 255) / 256, 256, 0, stream>>>(ei, rowptr, cnt, csr_src);

    // Aggregates: 16 nodes per block (4 waves x 4 nodes)
    k_agg1<<<(NN + 15) / 16, 256, 0, stream>>>(rowptr, csr_src, as1, ad1, h1b, b1, heb, ixz1);

    // Layer 2
    k_gemm2<<<(NN + 4 * G2T * 16 - 1) / (4 * G2T * 16), 256, 0, stream>>>(heb, W2, aS2, aD2, h2b, as2, ad2);
    k_agg2<<<(NN + 15) / 16, 256, 0, stream>>>(rowptr, csr_src, as2, ad2, h2b, b2, out2, ixz2);
}

// Round 7
// 162.780 us; speedup vs baseline: 2.1921x; 1.1201x over previous
//
#include <hip/hip_runtime.h>
#include <math.h>

#define NN 100000
#define NE 640000
#define ET (NE + NN)          // edges + self loops = 740000
#define FIN 128
#define C1 64
#define C2 16
#define NEG_SLOPE 0.2f
#define SCAN_B 1024
#define SCAN_NB ((NN + SCAN_B - 1) / SCAN_B)   // 98
#define G1_BLOCKS ((NN + 127) / 128)           // gemm1 blocks (4 waves x 32 rows)
#define HIST_BLOCKS ((ET + 255) / 256)

typedef unsigned int uint32;
typedef __attribute__((ext_vector_type(8))) short bf16x8;
typedef __attribute__((ext_vector_type(4))) float f32x4;

static __device__ __forceinline__ float lrelu(float x) { return x > 0.f ? x : NEG_SLOPE * x; }
static __device__ __forceinline__ float softplusf(float x) {
    return fmaxf(x, 0.f) + log1pf(expf(-fabsf(x)));
}
static __device__ __forceinline__ unsigned short f2bf(float f) {   // RNE
    uint32 u = __float_as_uint(f);
    u += 0x7fffu + ((u >> 16) & 1u);
    return (unsigned short)(u >> 16);
}
static __device__ __forceinline__ float bf2f_lo(uint32 p) { return __uint_as_float(p << 16); }
static __device__ __forceinline__ float bf2f_hi(uint32 p) { return __uint_as_float(p & 0xffff0000u); }

// ---------------- fused Layer-1 GEMM (MFMA) + degree histogram ----------------
#define G1T 2
__global__ __launch_bounds__(256, 3) void k_g1hist(
        const float* __restrict__ x, const float* __restrict__ W1,
        const float* __restrict__ attS, const float* __restrict__ attD,
        unsigned short* __restrict__ h1b, float* __restrict__ as1, float* __restrict__ ad1,
        const int* __restrict__ ei, int* __restrict__ deg) {
    __shared__ uint32 xs[4][16][64];   // per-wave 16 rows x 128 bf16 (packed u32), slot-swizzled
    if (blockIdx.x >= G1_BLOCKS) {
        // histogram part (independent of GEMM)
        int i = (int)(blockIdx.x - G1_BLOCKS) * 256 + threadIdx.x;
        if (i < ET) {
            int dst = (i < NE) ? ei[NE + i] : (i - NE);
            atomicAdd(&deg[dst], 1);
        }
        return;
    }
    int lane = threadIdx.x & 63;
    int wv = threadIdx.x >> 6;
    int col = lane & 15;
    int g = lane >> 4;
    int wbase = (blockIdx.x * 4 + wv) * (G1T * 16);
    if (wbase >= NN) return;

    bf16x8 bfr[4][4];
#pragma unroll
    for (int t = 0; t < 4; t++)
#pragma unroll
        for (int j = 0; j < 4; j++) {
            int c = col + j * 16;
#pragma unroll
            for (int i = 0; i < 8; i++)
                bfr[t][j][i] = (short)f2bf(W1[(t * 32 + g * 8 + i) * C1 + c]);
        }
    float ats[4], atd[4];
#pragma unroll
    for (int j = 0; j < 4; j++) { ats[j] = attS[col + j * 16]; atd[j] = attD[col + j * 16]; }

    float2 px[16];
#pragma unroll
    for (int rr = 0; rr < 16; rr++) {
        int r = wbase + rr; if (r > NN - 1) r = NN - 1;
        px[rr] = *reinterpret_cast<const float2*>(&x[(size_t)r * FIN + lane * 2]);
    }

    for (int tl = 0; tl < G1T; tl++) {
        int tbase = wbase + tl * 16;
#pragma unroll
        for (int rr = 0; rr < 16; rr++) {
            uint32 v = (uint32)f2bf(px[rr].x) | ((uint32)f2bf(px[rr].y) << 16);
            int slot = (lane >> 2) ^ rr;
            xs[wv][rr][slot * 4 + (lane & 3)] = v;
        }
        __builtin_amdgcn_wave_barrier();
        bf16x8 a[4];
#pragma unroll
        for (int t = 0; t < 4; t++) {
            int slot = (t * 4 + g) ^ col;
            a[t] = *reinterpret_cast<const bf16x8*>(&xs[wv][col][slot * 4]);
        }
        __builtin_amdgcn_wave_barrier();
        if (tl + 1 < G1T) {
#pragma unroll
            for (int rr = 0; rr < 16; rr++) {
                int r = tbase + 16 + rr; if (r > NN - 1) r = NN - 1;
                px[rr] = *reinterpret_cast<const float2*>(&x[(size_t)r * FIN + lane * 2]);
            }
        }
        f32x4 acc[4];
#pragma unroll
        for (int j = 0; j < 4; j++) acc[j] = (f32x4){0.f, 0.f, 0.f, 0.f};
#pragma unroll
        for (int t = 0; t < 4; t++)
#pragma unroll
            for (int j = 0; j < 4; j++)
                acc[j] = __builtin_amdgcn_mfma_f32_16x16x32_bf16(a[t], bfr[t][j], acc[j], 0, 0, 0);
        float sA[4] = {0.f, 0.f, 0.f, 0.f}, sD[4] = {0.f, 0.f, 0.f, 0.f};
#pragma unroll
        for (int reg = 0; reg < 4; reg++) {
            int row = tbase + g * 4 + reg;
            bool ok = row < NN;
#pragma unroll
            for (int j = 0; j < 4; j++) {
                float v = acc[j][reg];
                if (ok) h1b[(size_t)row * C1 + col + j * 16] = f2bf(v);
                sA[reg] = fmaf(v, ats[j], sA[reg]);
                sD[reg] = fmaf(v, atd[j], sD[reg]);
            }
        }
#pragma unroll
        for (int off = 8; off; off >>= 1)
#pragma unroll
            for (int reg = 0; reg < 4; reg++) {
                sA[reg] += __shfl_xor(sA[reg], off);
                sD[reg] += __shfl_xor(sD[reg], off);
            }
        if (col == 0) {
#pragma unroll
            for (int reg = 0; reg < 4; reg++) {
                int row = tbase + g * 4 + reg;
                if (row < NN) { as1[row] = sA[reg]; ad1[row] = sD[reg]; }
            }
        }
    }
}

// ---------------- CSR scan chain ----------------
__global__ void k_scan1(const int* __restrict__ deg, int* __restrict__ incl, int* __restrict__ bsum) {
    __shared__ int s[SCAN_B];
    int ti = threadIdx.x;
    int i = blockIdx.x * SCAN_B + ti;
    int v = (i < NN) ? deg[i] : 0;
    s[ti] = v; __syncthreads();
    for (int d = 1; d < SCAN_B; d <<= 1) {
        int t = (ti >= d) ? s[ti - d] : 0;
        __syncthreads();
        s[ti] += t;
        __syncthreads();
    }
    if (i < NN) incl[i] = s[ti];
    if (ti == SCAN_B - 1) bsum[blockIdx.x] = s[ti];
}

__global__ void k_scan2(const int* __restrict__ bsum, int* __restrict__ boff) {
    __shared__ int s[128];
    int ti = threadIdx.x;
    int v = (ti < SCAN_NB) ? bsum[ti] : 0;
    s[ti] = v; __syncthreads();
    for (int d = 1; d < 128; d <<= 1) {
        int t = (ti >= d) ? s[ti - d] : 0;
        __syncthreads();
        s[ti] += t;
        __syncthreads();
    }
    if (ti < SCAN_NB) boff[ti] = s[ti] - v;   // exclusive
}

__global__ void k_scan3(const int* __restrict__ incl, const int* __restrict__ boff, int* __restrict__ rowptr) {
    int i = blockIdx.x * blockDim.x + threadIdx.x;
    if (i < NN) rowptr[i + 1] = incl[i] + boff[i >> 10];
    if (i == 0) rowptr[0] = 0;
}

__global__ void k_scatter(const int* __restrict__ ei, const int* __restrict__ rowptr,
                          int* __restrict__ cnt, int* __restrict__ csr_src) {
    int i = blockIdx.x * blockDim.x + threadIdx.x;
    if (i >= ET) return;
    int src, dst;
    if (i < NE) { src = ei[i]; dst = ei[NE + i]; }
    else        { src = i - NE; dst = src; }
    int pos = rowptr[dst] + atomicAdd(&cnt[dst], 1);
    csr_src[pos] = src;
}

// ---------------- Layer 1 aggregate: 4 nodes/wave, 16 lanes/node, 4-deep MLP ----------------
__global__ __launch_bounds__(256, 8) void k_agg1(
        const int* __restrict__ rowptr, const int* __restrict__ csr_src,
        const float* __restrict__ as1, const float* __restrict__ ad1,
        const unsigned short* __restrict__ h1b, const float* __restrict__ b1,
        unsigned short* __restrict__ heb, float* __restrict__ ixz1) {
    int lane = threadIdx.x & 63;
    int wid = (blockIdx.x * blockDim.x + threadIdx.x) >> 6;
    int grp = lane >> 4, gl = lane & 15;
    int gbase = grp << 4;
    int node = wid * 4 + grp;
    if (node >= NN) return;
    int start = rowptr[node], end = rowptr[node + 1];
    int deg = end - start;
    float adn = ad1[node];
    float4 o;

    if (deg <= 16) {
        int e = start + (gl < deg ? gl : 0);
        int s_l = csr_src[e];
        float al = (gl < deg) ? lrelu(as1[s_l] + adn) : -1e30f;
        float m = al;
#pragma unroll
        for (int off = 8; off; off >>= 1) m = fmaxf(m, __shfl_xor(m, off));
        float wl = (gl < deg) ? expf(al - m) : 0.f;
        float den = wl;
#pragma unroll
        for (int off = 8; off; off >>= 1) den += __shfl_xor(den, off);
        wl *= 1.f / (den + 1e-16f);
        float4 acc = make_float4(0.f, 0.f, 0.f, 0.f);
        int dpad = (deg + 3) & ~3;     // <= 16; slots past deg contribute weight 0 (wl=0 there)
        for (int e0 = 0; e0 < dpad; e0 += 4) {
            float w0 = __shfl(wl, gbase | e0);
            float w1 = __shfl(wl, gbase | (e0 + 1));
            float w2 = __shfl(wl, gbase | (e0 + 2));
            float w3 = __shfl(wl, gbase | (e0 + 3));
            int s0 = __shfl(s_l, gbase | e0);
            int s1 = __shfl(s_l, gbase | (e0 + 1));
            int s2 = __shfl(s_l, gbase | (e0 + 2));
            int s3 = __shfl(s_l, gbase | (e0 + 3));
            uint2 p0 = *reinterpret_cast<const uint2*>(&h1b[(size_t)s0 * C1 + gl * 4]);
            uint2 p1 = *reinterpret_cast<const uint2*>(&h1b[(size_t)s1 * C1 + gl * 4]);
            uint2 p2 = *reinterpret_cast<const uint2*>(&h1b[(size_t)s2 * C1 + gl * 4]);
            uint2 p3 = *reinterpret_cast<const uint2*>(&h1b[(size_t)s3 * C1 + gl * 4]);
            acc.x = fmaf(w0, bf2f_lo(p0.x), acc.x);
            acc.y = fmaf(w0, bf2f_hi(p0.x), acc.y);
            acc.z = fmaf(w0, bf2f_lo(p0.y), acc.z);
            acc.w = fmaf(w0, bf2f_hi(p0.y), acc.w);
            acc.x = fmaf(w1, bf2f_lo(p1.x), acc.x);
            acc.y = fmaf(w1, bf2f_hi(p1.x), acc.y);
            acc.z = fmaf(w1, bf2f_lo(p1.y), acc.z);
            acc.w = fmaf(w1, bf2f_hi(p1.y), acc.w);
            acc.x = fmaf(w2, bf2f_lo(p2.x), acc.x);
            acc.y = fmaf(w2, bf2f_hi(p2.x), acc.y);
            acc.z = fmaf(w2, bf2f_lo(p2.y), acc.z);
            acc.w = fmaf(w2, bf2f_hi(p2.y), acc.w);
            acc.x = fmaf(w3, bf2f_lo(p3.x), acc.x);
            acc.y = fmaf(w3, bf2f_hi(p3.x), acc.y);
            acc.z = fmaf(w3, bf2f_lo(p3.y), acc.z);
            acc.w = fmaf(w3, bf2f_hi(p3.y), acc.w);
        }
        o = acc;
    } else {
        // rare: deg > 16 (~0.06% of nodes)
        float m = -1e30f;
        for (int e = start + gl; e < end; e += 16) m = fmaxf(m, lrelu(as1[csr_src[e]] + adn));
#pragma unroll
        for (int off = 8; off; off >>= 1) m = fmaxf(m, __shfl_xor(m, off));
        float den = 0.f;
        for (int e = start + gl; e < end; e += 16) den += expf(lrelu(as1[csr_src[e]] + adn) - m);
#pragma unroll
        for (int off = 8; off; off >>= 1) den += __shfl_xor(den, off);
        float inv = 1.f / (den + 1e-16f);
        float4 acc = make_float4(0.f, 0.f, 0.f, 0.f);
        for (int e = start; e < end; e++) {
            int s = csr_src[e];
            float wgt = expf(lrelu(as1[s] + adn) - m) * inv;
            uint2 p = *reinterpret_cast<const uint2*>(&h1b[(size_t)s * C1 + gl * 4]);
            acc.x = fmaf(wgt, bf2f_lo(p.x), acc.x);
            acc.y = fmaf(wgt, bf2f_hi(p.x), acc.y);
            acc.z = fmaf(wgt, bf2f_lo(p.y), acc.z);
            acc.w = fmaf(wgt, bf2f_hi(p.y), acc.w);
        }
        o = acc;
    }
    float4 bv = *reinterpret_cast<const float4*>(&b1[gl * 4]);
    o.x += bv.x; o.y += bv.y; o.z += bv.z; o.w += bv.w;
    float4 he;
    he.x = o.x > 0.f ? o.x : expm1f(o.x);
    he.y = o.y > 0.f ? o.y : expm1f(o.y);
    he.z = o.z > 0.f ? o.z : expm1f(o.z);
    he.w = o.w > 0.f ? o.w : expm1f(o.w);
    uint2 hw;
    hw.x = (uint32)f2bf(he.x) | ((uint32)f2bf(he.y) << 16);
    hw.y = (uint32)f2bf(he.z) | ((uint32)f2bf(he.w) << 16);
    *reinterpret_cast<uint2*>(&heb[(size_t)node * C1 + gl * 4]) = hw;
    float4 oth;
    oth.x = __shfl_down(o.x, 8);
    oth.y = __shfl_down(o.y, 8);
    oth.z = __shfl_down(o.z, 8);
    oth.w = __shfl_down(o.w, 8);
    if (gl < 8) {
        float4 kl; float sd;
        sd = softplusf(oth.x) + 1e-10f; kl.x = -logf(sd) + 0.5f * (sd * sd + o.x * o.x - 1.f);
        sd = softplusf(oth.y) + 1e-10f; kl.y = -logf(sd) + 0.5f * (sd * sd + o.y * o.y - 1.f);
        sd = softplusf(oth.z) + 1e-10f; kl.z = -logf(sd) + 0.5f * (sd * sd + o.z * o.z - 1.f);
        sd = softplusf(oth.w) + 1e-10f; kl.w = -logf(sd) + 0.5f * (sd * sd + o.w * o.w - 1.f);
        *reinterpret_cast<float4*>(&ixz1[(size_t)node * 32 + gl * 4]) = kl;
    }
}

// ---------------- Layer 2 GEMM (MFMA bf16): h2 = elu(out1) @ W2, + attention dots ----------------
#define G2T 4
__global__ __launch_bounds__(256, 4) void k_gemm2(
        const unsigned short* __restrict__ heb, const float* __restrict__ W2,
        const float* __restrict__ attS, const float* __restrict__ attD,
        unsigned short* __restrict__ h2b, float* __restrict__ as2, float* __restrict__ ad2) {
    int lane = threadIdx.x & 63;
    int wv = threadIdx.x >> 6;
    int col = lane & 15, g = lane >> 4;
    int wbase = (blockIdx.x * 4 + wv) * (G2T * 16);
    if (wbase >= NN) return;
    bf16x8 bfr[2];
#pragma unroll
    for (int t = 0; t < 2; t++)
#pragma unroll
        for (int i = 0; i < 8; i++)
            bfr[t][i] = (short)f2bf(W2[(t * 32 + g * 8 + i) * C2 + col]);
    float ats = attS[col], atd = attD[col];
#pragma unroll
    for (int tl = 0; tl < G2T; tl++) {
        int tbase = wbase + tl * 16;
        if (tbase >= NN) break;
        int arow = tbase + col; if (arow > NN - 1) arow = NN - 1;
        bf16x8 a0 = *reinterpret_cast<const bf16x8*>(&heb[(size_t)arow * C1 + g * 8]);
        bf16x8 a1 = *reinterpret_cast<const bf16x8*>(&heb[(size_t)arow * C1 + 32 + g * 8]);
        f32x4 acc = (f32x4){0.f, 0.f, 0.f, 0.f};
        acc = __builtin_amdgcn_mfma_f32_16x16x32_bf16(a0, bfr[0], acc, 0, 0, 0);
        acc = __builtin_amdgcn_mfma_f32_16x16x32_bf16(a1, bfr[1], acc, 0, 0, 0);
        float sA[4], sD[4];
#pragma unroll
        for (int reg = 0; reg < 4; reg++) {
            int row = tbase + g * 4 + reg;
            if (row < NN) h2b[(size_t)row * C2 + col] = f2bf(acc[reg]);
            sA[reg] = acc[reg] * ats;
            sD[reg] = acc[reg] * atd;
        }
#pragma unroll
        for (int off = 8; off; off >>= 1)
#pragma unroll
            for (int reg = 0; reg < 4; reg++) {
                sA[reg] += __shfl_xor(sA[reg], off);
                sD[reg] += __shfl_xor(sD[reg], off);
            }
        if (col == 0) {
#pragma unroll
            for (int reg = 0; reg < 4; reg++) {
                int row = tbase + g * 4 + reg;
                if (row < NN) { as2[row] = sA[reg]; ad2[row] = sD[reg]; }
            }
        }
    }
}

// ---------------- Layer 2 aggregate: 4 nodes/wave, 16 lanes/node, 8 edges in flight ----------------
__global__ __launch_bounds__(256, 8) void k_agg2(
        const int* __restrict__ rowptr, const int* __restrict__ csr_src,
        const float* __restrict__ as2, const float* __restrict__ ad2,
        const unsigned short* __restrict__ h2b, const float* __restrict__ b2,
        float* __restrict__ out2, float* __restrict__ ixz2) {
    int lane = threadIdx.x & 63;
    int wid = (blockIdx.x * blockDim.x + threadIdx.x) >> 6;
    int grp = lane >> 4, gl = lane & 15;
    int gbase = grp << 4;
    int node = wid * 4 + grp;
    if (node >= NN) return;
    int start = rowptr[node], end = rowptr[node + 1];
    int deg = end - start;
    float adn = ad2[node];
    float out;

    if (deg <= 16) {
        int e = start + (gl < deg ? gl : 0);
        int s_l = csr_src[e];
        float al = (gl < deg) ? lrelu(as2[s_l] + adn) : -1e30f;
        float m = al;
#pragma unroll
        for (int off = 8; off; off >>= 1) m = fmaxf(m, __shfl_xor(m, off));
        float wl = (gl < deg) ? expf(al - m) : 0.f;
        float den = wl;
#pragma unroll
        for (int off = 8; off; off >>= 1) den += __shfl_xor(den, off);
        wl *= 1.f / (den + 1e-16f);
        // 4 lanes x 4 features, 8 edges in flight (2 x 4 edge-groups)
        int f4 = gl & 3, eg = gl >> 2;
        float4 acc = make_float4(0.f, 0.f, 0.f, 0.f);
        int dpad = (deg + 7) & ~7;     // <= 16
        for (int e0 = 0; e0 < dpad; e0 += 8) {
            int ea = e0 + eg, eb = e0 + 4 + eg;
            float wa = __shfl(wl, gbase | ea);
            float wb = __shfl(wl, gbase | eb);
            int sa = __shfl(s_l, gbase | ea);
            int sb = __shfl(s_l, gbase | eb);
            uint2 pa = *reinterpret_cast<const uint2*>(&h2b[(size_t)sa * C2 + f4 * 4]);
            uint2 pb = *reinterpret_cast<const uint2*>(&h2b[(size_t)sb * C2 + f4 * 4]);
            acc.x = fmaf(wa, bf2f_lo(pa.x), acc.x);
            acc.y = fmaf(wa, bf2f_hi(pa.x), acc.y);
            acc.z = fmaf(wa, bf2f_lo(pa.y), acc.z);
            acc.w = fmaf(wa, bf2f_hi(pa.y), acc.w);
            acc.x = fmaf(wb, bf2f_lo(pb.x), acc.x);
            acc.y = fmaf(wb, bf2f_hi(pb.x), acc.y);
            acc.z = fmaf(wb, bf2f_lo(pb.y), acc.z);
            acc.w = fmaf(wb, bf2f_hi(pb.y), acc.w);
        }
#pragma unroll
        for (int off = 4; off <= 8; off <<= 1) {
            acc.x += __shfl_xor(acc.x, off);
            acc.y += __shfl_xor(acc.y, off);
            acc.z += __shfl_xor(acc.z, off);
            acc.w += __shfl_xor(acc.w, off);
        }
        // transpose: lane gl owns feature gl (src lane gbase|(gl>>2), comp gl&3)
        int srcl = gbase | (gl >> 2);
        float t0 = __shfl(acc.x, srcl);
        float t1 = __shfl(acc.y, srcl);
        float t2 = __shfl(acc.z, srcl);
        float t3 = __shfl(acc.w, srcl);
        float t01 = (gl & 1) ? t1 : t0;
        float t23 = (gl & 1) ? t3 : t2;
        out = (gl & 2) ? t23 : t01;
    } else {
        // rare: deg > 16; lane gl owns feature gl
        float m = -1e30f;
        for (int e = start + gl; e < end; e += 16) m = fmaxf(m, lrelu(as2[csr_src[e]] + adn));
#pragma unroll
        for (int off = 8; off; off >>= 1) m = fmaxf(m, __shfl_xor(m, off));
        float den = 0.f;
        for (int e = start + gl; e < end; e += 16) den += expf(lrelu(as2[csr_src[e]] + adn) - m);
#pragma unroll
        for (int off = 8; off; off >>= 1) den += __shfl_xor(den, off);
        float inv = 1.f / (den + 1e-16f);
        float acc = 0.f;
        for (int e = start; e < end; e++) {
            int s = csr_src[e];
            float wgt = expf(lrelu(as2[s] + adn) - m) * inv;
            acc = fmaf(wgt, __uint_as_float(((uint32)h2b[(size_t)s * C2 + gl]) << 16), acc);
        }
        out = acc;
    }
    out += b2[gl];
    out2[(size_t)node * C2 + gl] = out;
    float other = __shfl_down(out, 8);
    if (gl < 8) {
        float sd = softplusf(other) + 1e-10f;
        float kl = -logf(sd) + 0.5f * (sd * sd + out * out - 1.f);
        ixz2[(size_t)node * 8 + gl] = kl;
    }
}

extern "C" void kernel_launch(void* const* d_in, const int* in_sizes, int n_in,
                              void* d_out, int out_size, void* d_ws, size_t ws_size,
                              hipStream_t stream) {
    const float* x     = (const float*)d_in[0];
    const int*   ei    = (const int*)d_in[1];
    const float* W1    = (const float*)d_in[2];
    const float* aS1   = (const float*)d_in[3];
    const float* aD1   = (const float*)d_in[4];
    const float* b1    = (const float*)d_in[5];
    const float* W2    = (const float*)d_in[6];
    const float* aS2   = (const float*)d_in[7];
    const float* aD2   = (const float*)d_in[8];
    const float* b2    = (const float*)d_in[9];

    float* out = (float*)d_out;
    float* out2 = out;                         // N*16
    float* ixz1 = out + (size_t)NN * C2;       // N*32
    float* ixz2 = ixz1 + (size_t)NN * 32;      // N*8

    char* p = (char*)d_ws;
    auto alloc = [&](size_t bytes) -> void* {
        void* r = (void*)p;
        p += (bytes + 255) & ~(size_t)255;
        return r;
    };
    int* deg     = (int*)alloc((size_t)NN * 4);
    int* cnt     = (int*)alloc((size_t)NN * 4);
    int* incl    = (int*)alloc((size_t)NN * 4);
    int* bsum    = (int*)alloc(512 * 4);
    int* boff    = (int*)alloc(512 * 4);
    int* rowptr  = (int*)alloc((size_t)(NN + 1) * 4);
    int* csr_src = (int*)alloc((size_t)ET * 4);
    unsigned short* h1b = (unsigned short*)alloc((size_t)NN * C1 * 2);
    float* as1   = (float*)alloc((size_t)NN * 4);
    float* ad1   = (float*)alloc((size_t)NN * 4);
    unsigned short* heb = (unsigned short*)alloc((size_t)NN * C1 * 2);
    unsigned short* h2b = (unsigned short*)alloc((size_t)NN * C2 * 2);
    float* as2   = (float*)alloc((size_t)NN * 4);
    float* ad2   = (float*)alloc((size_t)NN * 4);
    (void)ws_size; (void)in_sizes; (void)n_in; (void)out_size;

    // zero deg+cnt (contiguous region) without a kernel launch
    hipMemsetAsync(deg, 0, (size_t)((char*)incl - (char*)deg), stream);

    // fused Layer-1 GEMM + degree histogram
    k_g1hist<<<G1_BLOCKS + HIST_BLOCKS, 256, 0, stream>>>(x, W1, aS1, aD1, h1b, as1, ad1, ei, deg);

    // CSR scan + scatter
    k_scan1<<<SCAN_NB, SCAN_B, 0, stream>>>(deg, incl, bsum);
    k_scan2<<<1, 128, 0, stream>>>(bsum, boff);
    k_scan3<<<(NN + 255) / 256, 256, 0, stream>>>(incl, boff, rowptr);
    k_scatter<<<(ET + 255) / 256, 256, 0, stream>>>(ei, rowptr, cnt, csr_src);

    // Layer 1 aggregate (16 nodes/block)
    k_agg1<<<(NN + 15) / 16, 256, 0, stream>>>(rowptr, csr_src, as1, ad1, h1b, b1, heb, ixz1);

    // Layer 2
    k_gemm2<<<(NN + 4 * G2T * 16 - 1) / (4 * G2T * 16), 256, 0, stream>>>(heb, W2, aS2, aD2, h2b, as2, ad2);
    k_agg2<<<(NN + 15) / 16, 256, 0, stream>>>(rowptr, csr_src, as2, ad2, h2b, b2, out2, ixz2);
}

// Round 8
// 150.461 us; speedup vs baseline: 2.3716x; 1.0819x over previous
//
#include <hip/hip_runtime.h>
#include <math.h>

#define NN 100000
#define NE 640000
#define ET (NE + NN)          // edges + self loops = 740000
#define FIN 128
#define C1 64
#define C2 16
#define NEG_SLOPE 0.2f
#define SCAN_B 1024
#define SCAN_NB ((NN + SCAN_B - 1) / SCAN_B)   // 98
#define G1_BLOCKS ((NN + 127) / 128)           // gemm1 blocks (4 waves x 32 rows)
#define HIST_BLOCKS ((ET + 255) / 256)

typedef unsigned int uint32;
typedef __attribute__((ext_vector_type(8))) short bf16x8;
typedef __attribute__((ext_vector_type(4))) float f32x4;

static __device__ __forceinline__ float lrelu(float x) { return x > 0.f ? x : NEG_SLOPE * x; }
static __device__ __forceinline__ float softplusf(float x) {
    return fmaxf(x, 0.f) + log1pf(expf(-fabsf(x)));
}
static __device__ __forceinline__ unsigned short f2bf(float f) {   // RNE
    uint32 u = __float_as_uint(f);
    u += 0x7fffu + ((u >> 16) & 1u);
    return (unsigned short)(u >> 16);
}
static __device__ __forceinline__ float bf2f_lo(uint32 p) { return __uint_as_float(p << 16); }
static __device__ __forceinline__ float bf2f_hi(uint32 p) { return __uint_as_float(p & 0xffff0000u); }

// ---------------- fused Layer-1 GEMM (MFMA, reg-direct A, coalesced C) + degree histogram ----------------
#define G1T 2
__global__ __launch_bounds__(256, 3) void k_g1hist(
        const float* __restrict__ x, const float* __restrict__ W1,
        const float* __restrict__ attS, const float* __restrict__ attD,
        unsigned short* __restrict__ h1b, float* __restrict__ as1, float* __restrict__ ad1,
        const int* __restrict__ ei, int* __restrict__ deg) {
    __shared__ uint32 ts[4][16][36];   // per-wave C-transpose tile (rows 144B: 16B-aligned, banks ~2-way)
    if (blockIdx.x >= G1_BLOCKS) {
        // histogram part (independent of GEMM)
        int i = (int)(blockIdx.x - G1_BLOCKS) * 256 + threadIdx.x;
        if (i < ET) {
            int dst = (i < NE) ? ei[NE + i] : (i - NE);
            atomicAdd(&deg[dst], 1);
        }
        return;
    }
    int lane = threadIdx.x & 63;
    int wv = threadIdx.x >> 6;
    int col = lane & 15;
    int g = lane >> 4;
    int wbase = (blockIdx.x * 4 + wv) * (G1T * 16);
    if (wbase >= NN) return;

    // B fragments in registers: B[k][col] = W1[k*64+col]; lane: col=lane&15 (+16j), k=32t+8g+i
    bf16x8 bfr[4][4];
#pragma unroll
    for (int t = 0; t < 4; t++)
#pragma unroll
        for (int j = 0; j < 4; j++) {
            int c = col + j * 16;
#pragma unroll
            for (int i = 0; i < 8; i++)
                bfr[t][j][i] = (short)f2bf(W1[(t * 32 + g * 8 + i) * C1 + c]);
        }
    float ats[4], atd[4];
#pragma unroll
    for (int j = 0; j < 4; j++) { ats[j] = attS[col + j * 16]; atd[j] = attD[col + j * 16]; }

    for (int tl = 0; tl < G1T; tl++) {
        int tbase = wbase + tl * 16;
        // A-fragments straight from global: lane (col,g) reads 32B of row (tbase+col) per k-block t
        int arow = tbase + col; if (arow > NN - 1) arow = NN - 1;
        const float* xr = &x[(size_t)arow * FIN];
        float4 f0[4], f1[4];
#pragma unroll
        for (int t = 0; t < 4; t++) {
            f0[t] = *reinterpret_cast<const float4*>(&xr[t * 32 + g * 8]);
            f1[t] = *reinterpret_cast<const float4*>(&xr[t * 32 + g * 8 + 4]);
        }
        bf16x8 a[4];
#pragma unroll
        for (int t = 0; t < 4; t++) {
            a[t][0] = (short)f2bf(f0[t].x); a[t][1] = (short)f2bf(f0[t].y);
            a[t][2] = (short)f2bf(f0[t].z); a[t][3] = (short)f2bf(f0[t].w);
            a[t][4] = (short)f2bf(f1[t].x); a[t][5] = (short)f2bf(f1[t].y);
            a[t][6] = (short)f2bf(f1[t].z); a[t][7] = (short)f2bf(f1[t].w);
        }
        f32x4 acc[4];
#pragma unroll
        for (int j = 0; j < 4; j++) acc[j] = (f32x4){0.f, 0.f, 0.f, 0.f};
#pragma unroll
        for (int t = 0; t < 4; t++)
#pragma unroll
            for (int j = 0; j < 4; j++)
                acc[j] = __builtin_amdgcn_mfma_f32_16x16x32_bf16(a[t], bfr[t][j], acc[j], 0, 0, 0);

        // epilogue: C layout col=lane&15 (+16j), row(in tile)=g*4+reg  [m89-verified]
        float sA[4] = {0.f, 0.f, 0.f, 0.f}, sD[4] = {0.f, 0.f, 0.f, 0.f};
        unsigned short* tsw = (unsigned short*)&ts[wv][0][0];   // u16 view, row stride 72
#pragma unroll
        for (int reg = 0; reg < 4; reg++) {
            int trow = g * 4 + reg;
#pragma unroll
            for (int j = 0; j < 4; j++) {
                float v = acc[j][reg];
                tsw[trow * 72 + col + j * 16] = f2bf(v);
                sA[reg] = fmaf(v, ats[j], sA[reg]);
                sD[reg] = fmaf(v, atd[j], sD[reg]);
            }
        }
        __builtin_amdgcn_wave_barrier();
        // coalesced C store: lane covers bytes [lane*32, lane*32+32) of the 2KB tile
        {
            int rrow = lane >> 2, rq = lane & 3;
            uint4 w0 = *reinterpret_cast<const uint4*>(&ts[wv][rrow][rq * 8]);
            uint4 w1 = *reinterpret_cast<const uint4*>(&ts[wv][rrow][rq * 8 + 4]);
            int orow = tbase + rrow;
            if (orow < NN) {
                unsigned short* op = &h1b[(size_t)orow * C1 + rq * 16];
                *reinterpret_cast<uint4*>(op) = w0;
                *reinterpret_cast<uint4*>(op + 8) = w1;
            }
        }
        __builtin_amdgcn_wave_barrier();
#pragma unroll
        for (int off = 8; off; off >>= 1)
#pragma unroll
            for (int reg = 0; reg < 4; reg++) {
                sA[reg] += __shfl_xor(sA[reg], off);
                sD[reg] += __shfl_xor(sD[reg], off);
            }
        if (col == 0) {
#pragma unroll
            for (int reg = 0; reg < 4; reg++) {
                int row = tbase + g * 4 + reg;
                if (row < NN) { as1[row] = sA[reg]; ad1[row] = sD[reg]; }
            }
        }
    }
}

// ---------------- CSR scan chain ----------------
__global__ void k_scan1(const int* __restrict__ deg, int* __restrict__ incl, int* __restrict__ bsum) {
    __shared__ int s[SCAN_B];
    int ti = threadIdx.x;
    int i = blockIdx.x * SCAN_B + ti;
    int v = (i < NN) ? deg[i] : 0;
    s[ti] = v; __syncthreads();
    for (int d = 1; d < SCAN_B; d <<= 1) {
        int t = (ti >= d) ? s[ti - d] : 0;
        __syncthreads();
        s[ti] += t;
        __syncthreads();
    }
    if (i < NN) incl[i] = s[ti];
    if (ti == SCAN_B - 1) bsum[blockIdx.x] = s[ti];
}

__global__ void k_scan2(const int* __restrict__ bsum, int* __restrict__ boff) {
    __shared__ int s[128];
    int ti = threadIdx.x;
    int v = (ti < SCAN_NB) ? bsum[ti] : 0;
    s[ti] = v; __syncthreads();
    for (int d = 1; d < 128; d <<= 1) {
        int t = (ti >= d) ? s[ti - d] : 0;
        __syncthreads();
        s[ti] += t;
        __syncthreads();
    }
    if (ti < SCAN_NB) boff[ti] = s[ti] - v;   // exclusive
}

__global__ void k_scan3(const int* __restrict__ incl, const int* __restrict__ boff, int* __restrict__ rowptr) {
    int i = blockIdx.x * blockDim.x + threadIdx.x;
    if (i < NN) rowptr[i + 1] = incl[i] + boff[i >> 10];
    if (i == 0) rowptr[0] = 0;
}

__global__ void k_scatter(const int* __restrict__ ei, const int* __restrict__ rowptr,
                          int* __restrict__ cnt, int* __restrict__ csr_src) {
    int i = blockIdx.x * blockDim.x + threadIdx.x;
    if (i >= ET) return;
    int src, dst;
    if (i < NE) { src = ei[i]; dst = ei[NE + i]; }
    else        { src = i - NE; dst = src; }
    int pos = rowptr[dst] + atomicAdd(&cnt[dst], 1);
    csr_src[pos] = src;
}

// ---------------- Layer 1 aggregate: 4 nodes/wave, 16 lanes/node, 4-deep MLP ----------------
__global__ __launch_bounds__(256, 8) void k_agg1(
        const int* __restrict__ rowptr, const int* __restrict__ csr_src,
        const float* __restrict__ as1, const float* __restrict__ ad1,
        const unsigned short* __restrict__ h1b, const float* __restrict__ b1,
        unsigned short* __restrict__ heb, float* __restrict__ ixz1) {
    int lane = threadIdx.x & 63;
    int wid = (blockIdx.x * blockDim.x + threadIdx.x) >> 6;
    int grp = lane >> 4, gl = lane & 15;
    int gbase = grp << 4;
    int node = wid * 4 + grp;
    if (node >= NN) return;
    int start = rowptr[node], end = rowptr[node + 1];
    int deg = end - start;
    float adn = ad1[node];
    float4 o;

    if (deg <= 16) {
        int e = start + (gl < deg ? gl : 0);
        int s_l = csr_src[e];
        float al = (gl < deg) ? lrelu(as1[s_l] + adn) : -1e30f;
        float m = al;
#pragma unroll
        for (int off = 8; off; off >>= 1) m = fmaxf(m, __shfl_xor(m, off));
        float wl = (gl < deg) ? expf(al - m) : 0.f;
        float den = wl;
#pragma unroll
        for (int off = 8; off; off >>= 1) den += __shfl_xor(den, off);
        wl *= 1.f / (den + 1e-16f);
        float4 acc = make_float4(0.f, 0.f, 0.f, 0.f);
        int dpad = (deg + 3) & ~3;     // <= 16; slots past deg contribute weight 0 (wl=0 there)
        for (int e0 = 0; e0 < dpad; e0 += 4) {
            float w0 = __shfl(wl, gbase | e0);
            float w1 = __shfl(wl, gbase | (e0 + 1));
            float w2 = __shfl(wl, gbase | (e0 + 2));
            float w3 = __shfl(wl, gbase | (e0 + 3));
            int s0 = __shfl(s_l, gbase | e0);
            int s1 = __shfl(s_l, gbase | (e0 + 1));
            int s2 = __shfl(s_l, gbase | (e0 + 2));
            int s3 = __shfl(s_l, gbase | (e0 + 3));
            uint2 p0 = *reinterpret_cast<const uint2*>(&h1b[(size_t)s0 * C1 + gl * 4]);
            uint2 p1 = *reinterpret_cast<const uint2*>(&h1b[(size_t)s1 * C1 + gl * 4]);
            uint2 p2 = *reinterpret_cast<const uint2*>(&h1b[(size_t)s2 * C1 + gl * 4]);
            uint2 p3 = *reinterpret_cast<const uint2*>(&h1b[(size_t)s3 * C1 + gl * 4]);
            acc.x = fmaf(w0, bf2f_lo(p0.x), acc.x);
            acc.y = fmaf(w0, bf2f_hi(p0.x), acc.y);
            acc.z = fmaf(w0, bf2f_lo(p0.y), acc.z);
            acc.w = fmaf(w0, bf2f_hi(p0.y), acc.w);
            acc.x = fmaf(w1, bf2f_lo(p1.x), acc.x);
            acc.y = fmaf(w1, bf2f_hi(p1.x), acc.y);
            acc.z = fmaf(w1, bf2f_lo(p1.y), acc.z);
            acc.w = fmaf(w1, bf2f_hi(p1.y), acc.w);
            acc.x = fmaf(w2, bf2f_lo(p2.x), acc.x);
            acc.y = fmaf(w2, bf2f_hi(p2.x), acc.y);
            acc.z = fmaf(w2, bf2f_lo(p2.y), acc.z);
            acc.w = fmaf(w2, bf2f_hi(p2.y), acc.w);
            acc.x = fmaf(w3, bf2f_lo(p3.x), acc.x);
            acc.y = fmaf(w3, bf2f_hi(p3.x), acc.y);
            acc.z = fmaf(w3, bf2f_lo(p3.y), acc.z);
            acc.w = fmaf(w3, bf2f_hi(p3.y), acc.w);
        }
        o = acc;
    } else {
        // rare: deg > 16 (~0.06% of nodes)
        float m = -1e30f;
        for (int e = start + gl; e < end; e += 16) m = fmaxf(m, lrelu(as1[csr_src[e]] + adn));
#pragma unroll
        for (int off = 8; off; off >>= 1) m = fmaxf(m, __shfl_xor(m, off));
        float den = 0.f;
        for (int e = start + gl; e < end; e += 16) den += expf(lrelu(as1[csr_src[e]] + adn) - m);
#pragma unroll
        for (int off = 8; off; off >>= 1) den += __shfl_xor(den, off);
        float inv = 1.f / (den + 1e-16f);
        float4 acc = make_float4(0.f, 0.f, 0.f, 0.f);
        for (int e = start; e < end; e++) {
            int s = csr_src[e];
            float wgt = expf(lrelu(as1[s] + adn) - m) * inv;
            uint2 p = *reinterpret_cast<const uint2*>(&h1b[(size_t)s * C1 + gl * 4]);
            acc.x = fmaf(wgt, bf2f_lo(p.x), acc.x);
            acc.y = fmaf(wgt, bf2f_hi(p.x), acc.y);
            acc.z = fmaf(wgt, bf2f_lo(p.y), acc.z);
            acc.w = fmaf(wgt, bf2f_hi(p.y), acc.w);
        }
        o = acc;
    }
    float4 bv = *reinterpret_cast<const float4*>(&b1[gl * 4]);
    o.x += bv.x; o.y += bv.y; o.z += bv.z; o.w += bv.w;
    float4 he;
    he.x = o.x > 0.f ? o.x : expm1f(o.x);
    he.y = o.y > 0.f ? o.y : expm1f(o.y);
    he.z = o.z > 0.f ? o.z : expm1f(o.z);
    he.w = o.w > 0.f ? o.w : expm1f(o.w);
    uint2 hw;
    hw.x = (uint32)f2bf(he.x) | ((uint32)f2bf(he.y) << 16);
    hw.y = (uint32)f2bf(he.z) | ((uint32)f2bf(he.w) << 16);
    *reinterpret_cast<uint2*>(&heb[(size_t)node * C1 + gl * 4]) = hw;
    float4 oth;
    oth.x = __shfl_down(o.x, 8);
    oth.y = __shfl_down(o.y, 8);
    oth.z = __shfl_down(o.z, 8);
    oth.w = __shfl_down(o.w, 8);
    if (gl < 8) {
        float4 kl; float sd;
        sd = softplusf(oth.x) + 1e-10f; kl.x = -logf(sd) + 0.5f * (sd * sd + o.x * o.x - 1.f);
        sd = softplusf(oth.y) + 1e-10f; kl.y = -logf(sd) + 0.5f * (sd * sd + o.y * o.y - 1.f);
        sd = softplusf(oth.z) + 1e-10f; kl.z = -logf(sd) + 0.5f * (sd * sd + o.z * o.z - 1.f);
        sd = softplusf(oth.w) + 1e-10f; kl.w = -logf(sd) + 0.5f * (sd * sd + o.w * o.w - 1.f);
        *reinterpret_cast<float4*>(&ixz1[(size_t)node * 32 + gl * 4]) = kl;
    }
}

// ---------------- Layer 2 GEMM (MFMA bf16): h2 = elu(out1) @ W2, + attention dots ----------------
#define G2T 4
__global__ __launch_bounds__(256, 4) void k_gemm2(
        const unsigned short* __restrict__ heb, const float* __restrict__ W2,
        const float* __restrict__ attS, const float* __restrict__ attD,
        unsigned short* __restrict__ h2b, float* __restrict__ as2, float* __restrict__ ad2) {
    int lane = threadIdx.x & 63;
    int wv = threadIdx.x >> 6;
    int col = lane & 15, g = lane >> 4;
    int wbase = (blockIdx.x * 4 + wv) * (G2T * 16);
    if (wbase >= NN) return;
    bf16x8 bfr[2];
#pragma unroll
    for (int t = 0; t < 2; t++)
#pragma unroll
        for (int i = 0; i < 8; i++)
            bfr[t][i] = (short)f2bf(W2[(t * 32 + g * 8 + i) * C2 + col]);
    float ats = attS[col], atd = attD[col];
#pragma unroll
    for (int tl = 0; tl < G2T; tl++) {
        int tbase = wbase + tl * 16;
        if (tbase >= NN) break;
        int arow = tbase + col; if (arow > NN - 1) arow = NN - 1;
        bf16x8 a0 = *reinterpret_cast<const bf16x8*>(&heb[(size_t)arow * C1 + g * 8]);
        bf16x8 a1 = *reinterpret_cast<const bf16x8*>(&heb[(size_t)arow * C1 + 32 + g * 8]);
        f32x4 acc = (f32x4){0.f, 0.f, 0.f, 0.f};
        acc = __builtin_amdgcn_mfma_f32_16x16x32_bf16(a0, bfr[0], acc, 0, 0, 0);
        acc = __builtin_amdgcn_mfma_f32_16x16x32_bf16(a1, bfr[1], acc, 0, 0, 0);
        float sA[4], sD[4];
#pragma unroll
        for (int reg = 0; reg < 4; reg++) {
            int row = tbase + g * 4 + reg;
            if (row < NN) h2b[(size_t)row * C2 + col] = f2bf(acc[reg]);
            sA[reg] = acc[reg] * ats;
            sD[reg] = acc[reg] * atd;
        }
#pragma unroll
        for (int off = 8; off; off >>= 1)
#pragma unroll
            for (int reg = 0; reg < 4; reg++) {
                sA[reg] += __shfl_xor(sA[reg], off);
                sD[reg] += __shfl_xor(sD[reg], off);
            }
        if (col == 0) {
#pragma unroll
            for (int reg = 0; reg < 4; reg++) {
                int row = tbase + g * 4 + reg;
                if (row < NN) { as2[row] = sA[reg]; ad2[row] = sD[reg]; }
            }
        }
    }
}

// ---------------- Layer 2 aggregate: 4 nodes/wave, 16 lanes/node, 8 edges in flight ----------------
__global__ __launch_bounds__(256, 8) void k_agg2(
        const int* __restrict__ rowptr, const int* __restrict__ csr_src,
        const float* __restrict__ as2, const float* __restrict__ ad2,
        const unsigned short* __restrict__ h2b, const float* __restrict__ b2,
        float* __restrict__ out2, float* __restrict__ ixz2) {
    int lane = threadIdx.x & 63;
    int wid = (blockIdx.x * blockDim.x + threadIdx.x) >> 6;
    int grp = lane >> 4, gl = lane & 15;
    int gbase = grp << 4;
    int node = wid * 4 + grp;
    if (node >= NN) return;
    int start = rowptr[node], end = rowptr[node + 1];
    int deg = end - start;
    float adn = ad2[node];
    float out;

    if (deg <= 16) {
        int e = start + (gl < deg ? gl : 0);
        int s_l = csr_src[e];
        float al = (gl < deg) ? lrelu(as2[s_l] + adn) : -1e30f;
        float m = al;
#pragma unroll
        for (int off = 8; off; off >>= 1) m = fmaxf(m, __shfl_xor(m, off));
        float wl = (gl < deg) ? expf(al - m) : 0.f;
        float den = wl;
#pragma unroll
        for (int off = 8; off; off >>= 1) den += __shfl_xor(den, off);
        wl *= 1.f / (den + 1e-16f);
        // 4 lanes x 4 features, 8 edges in flight (2 x 4 edge-groups)
        int f4 = gl & 3, eg = gl >> 2;
        float4 acc = make_float4(0.f, 0.f, 0.f, 0.f);
        int dpad = (deg + 7) & ~7;     // <= 16
        for (int e0 = 0; e0 < dpad; e0 += 8) {
            int ea = e0 + eg, eb = e0 + 4 + eg;
            float wa = __shfl(wl, gbase | ea);
            float wb = __shfl(wl, gbase | eb);
            int sa = __shfl(s_l, gbase | ea);
            int sb = __shfl(s_l, gbase | eb);
            uint2 pa = *reinterpret_cast<const uint2*>(&h2b[(size_t)sa * C2 + f4 * 4]);
            uint2 pb = *reinterpret_cast<const uint2*>(&h2b[(size_t)sb * C2 + f4 * 4]);
            acc.x = fmaf(wa, bf2f_lo(pa.x), acc.x);
            acc.y = fmaf(wa, bf2f_hi(pa.x), acc.y);
            acc.z = fmaf(wa, bf2f_lo(pa.y), acc.z);
            acc.w = fmaf(wa, bf2f_hi(pa.y), acc.w);
            acc.x = fmaf(wb, bf2f_lo(pb.x), acc.x);
            acc.y = fmaf(wb, bf2f_hi(pb.x), acc.y);
            acc.z = fmaf(wb, bf2f_lo(pb.y), acc.z);
            acc.w = fmaf(wb, bf2f_hi(pb.y), acc.w);
        }
#pragma unroll
        for (int off = 4; off <= 8; off <<= 1) {
            acc.x += __shfl_xor(acc.x, off);
            acc.y += __shfl_xor(acc.y, off);
            acc.z += __shfl_xor(acc.z, off);
            acc.w += __shfl_xor(acc.w, off);
        }
        // transpose: lane gl owns feature gl (src lane gbase|(gl>>2), comp gl&3)
        int srcl = gbase | (gl >> 2);
        float t0 = __shfl(acc.x, srcl);
        float t1 = __shfl(acc.y, srcl);
        float t2 = __shfl(acc.z, srcl);
        float t3 = __shfl(acc.w, srcl);
        float t01 = (gl & 1) ? t1 : t0;
        float t23 = (gl & 1) ? t3 : t2;
        out = (gl & 2) ? t23 : t01;
    } else {
        // rare: deg > 16; lane gl owns feature gl
        float m = -1e30f;
        for (int e = start + gl; e < end; e += 16) m = fmaxf(m, lrelu(as2[csr_src[e]] + adn));
#pragma unroll
        for (int off = 8; off; off >>= 1) m = fmaxf(m, __shfl_xor(m, off));
        float den = 0.f;
        for (int e = start + gl; e < end; e += 16) den += expf(lrelu(as2[csr_src[e]] + adn) - m);
#pragma unroll
        for (int off = 8; off; off >>= 1) den += __shfl_xor(den, off);
        float inv = 1.f / (den + 1e-16f);
        float acc = 0.f;
        for (int e = start; e < end; e++) {
            int s = csr_src[e];
            float wgt = expf(lrelu(as2[s] + adn) - m) * inv;
            acc = fmaf(wgt, __uint_as_float(((uint32)h2b[(size_t)s * C2 + gl]) << 16), acc);
        }
        out = acc;
    }
    out += b2[gl];
    out2[(size_t)node * C2 + gl] = out;
    float other = __shfl_down(out, 8);
    if (gl < 8) {
        float sd = softplusf(other) + 1e-10f;
        float kl = -logf(sd) + 0.5f * (sd * sd + out * out - 1.f);
        ixz2[(size_t)node * 8 + gl] = kl;
    }
}

extern "C" void kernel_launch(void* const* d_in, const int* in_sizes, int n_in,
                              void* d_out, int out_size, void* d_ws, size_t ws_size,
                              hipStream_t stream) {
    const float* x     = (const float*)d_in[0];
    const int*   ei    = (const int*)d_in[1];
    const float* W1    = (const float*)d_in[2];
    const float* aS1   = (const float*)d_in[3];
    const float* aD1   = (const float*)d_in[4];
    const float* b1    = (const float*)d_in[5];
    const float* W2    = (const float*)d_in[6];
    const float* aS2   = (const float*)d_in[7];
    const float* aD2   = (const float*)d_in[8];
    const float* b2    = (const float*)d_in[9];

    float* out = (float*)d_out;
    float* out2 = out;                         // N*16
    float* ixz1 = out + (size_t)NN * C2;       // N*32
    float* ixz2 = ixz1 + (size_t)NN * 32;      // N*8

    char* p = (char*)d_ws;
    auto alloc = [&](size_t bytes) -> void* {
        void* r = (void*)p;
        p += (bytes + 255) & ~(size_t)255;
        return r;
    };
    int* deg     = (int*)alloc((size_t)NN * 4);
    int* cnt     = (int*)alloc((size_t)NN * 4);
    int* incl    = (int*)alloc((size_t)NN * 4);
    int* bsum    = (int*)alloc(512 * 4);
    int* boff    = (int*)alloc(512 * 4);
    int* rowptr  = (int*)alloc((size_t)(NN + 1) * 4);
    int* csr_src = (int*)alloc((size_t)ET * 4);
    unsigned short* h1b = (unsigned short*)alloc((size_t)NN * C1 * 2);
    float* as1   = (float*)alloc((size_t)NN * 4);
    float* ad1   = (float*)alloc((size_t)NN * 4);
    unsigned short* heb = (unsigned short*)alloc((size_t)NN * C1 * 2);
    unsigned short* h2b = (unsigned short*)alloc((size_t)NN * C2 * 2);
    float* as2   = (float*)alloc((size_t)NN * 4);
    float* ad2   = (float*)alloc((size_t)NN * 4);
    (void)ws_size; (void)in_sizes; (void)n_in; (void)out_size;

    // zero deg+cnt (contiguous region) without a kernel launch
    hipMemsetAsync(deg, 0, (size_t)((char*)incl - (char*)deg), stream);

    // fused Layer-1 GEMM + degree histogram
    k_g1hist<<<G1_BLOCKS + HIST_BLOCKS, 256, 0, stream>>>(x, W1, aS1, aD1, h1b, as1, ad1, ei, deg);

    // CSR scan + scatter
    k_scan1<<<SCAN_NB, SCAN_B, 0, stream>>>(deg, incl, bsum);
    k_scan2<<<1, 128, 0, stream>>>(bsum, boff);
    k_scan3<<<(NN + 255) / 256, 256, 0, stream>>>(incl, boff, rowptr);
    k_scatter<<<(ET + 255) / 256, 256, 0, stream>>>(ei, rowptr, cnt, csr_src);

    // Layer 1 aggregate (16 nodes/block)
    k_agg1<<<(NN + 15) / 16, 256, 0, stream>>>(rowptr, csr_src, as1, ad1, h1b, b1, heb, ixz1);

    // Layer 2
    k_gemm2<<<(NN + 4 * G2T * 16 - 1) / (4 * G2T * 16), 256, 0, stream>>>(heb, W2, aS2, aD2, h2b, as2, ad2);
    k_agg2<<<(NN + 15) / 16, 256, 0, stream>>>(rowptr, csr_src, as2, ad2, h2b, b2, out2, ixz2);
}